// Round 1
// baseline (2425.112 us; speedup 1.0000x reference)
//
#include <hip/hip_runtime.h>

#define N_NODES 10000
#define BATCH 8
#define FIN 128
#define UNITS 32
#define NH1 4

// ---------------- GEMM: Hout[row][c] = sum_k X[row][k] * W[k][c] ----------------
// W staged in LDS (K*COLS floats). Block = 256 threads, handles 16 rows.
template<int K, int COLS>
__global__ void gemm_kernel(const float* __restrict__ X, const float* __restrict__ W,
                            float* __restrict__ Hout, int rows) {
    __shared__ float Ws[K * COLS];
    int tid = threadIdx.x;
    for (int i = tid; i < K * COLS; i += blockDim.x) Ws[i] = W[i];
    __syncthreads();
    const int ROWS_PER_BLOCK = 16;
    int c  = tid % COLS;
    int rg = tid / COLS;
    int rstride = blockDim.x / COLS;
    int row0 = blockIdx.x * ROWS_PER_BLOCK;
    for (int r = rg; r < ROWS_PER_BLOCK; r += rstride) {
        int row = row0 + r;
        if (row >= rows) break;
        const float4* xr4 = (const float4*)(X + (size_t)row * K);
        float acc = 0.f;
        #pragma unroll
        for (int k4 = 0; k4 < K / 4; ++k4) {
            float4 xv = xr4[k4];
            acc += xv.x * Ws[(4*k4+0)*COLS + c];
            acc += xv.y * Ws[(4*k4+1)*COLS + c];
            acc += xv.z * Ws[(4*k4+2)*COLS + c];
            acc += xv.w * Ws[(4*k4+3)*COLS + c];
        }
        Hout[(size_t)row * COLS + c] = acc;
    }
}

// ---------------- attention logits: es/ed[row*H+h] = dot(H[row][h*32..], a[h][..]) ----
template<int H>
__global__ void att_logits_kernel(const float* __restrict__ Hf,
                                  const float* __restrict__ a_src,
                                  const float* __restrict__ a_dst,
                                  float* __restrict__ es, float* __restrict__ ed,
                                  int rows) {
    int t = blockIdx.x * blockDim.x + threadIdx.x;
    if (t >= rows * H) return;
    int row = t / H, h = t % H;
    const float4* hv = (const float4*)(Hf + (size_t)row * (H * UNITS) + h * UNITS);
    const float4* as = (const float4*)(a_src + h * UNITS);
    const float4* ad = (const float4*)(a_dst + h * UNITS);
    float s = 0.f, d = 0.f;
    #pragma unroll
    for (int i = 0; i < UNITS / 4; ++i) {
        float4 x = hv[i], A = as[i], D = ad[i];
        s += x.x*A.x + x.y*A.y + x.z*A.z + x.w*A.w;
        d += x.x*D.x + x.y*D.y + x.z*D.z + x.w*D.w;
    }
    es[t] = s;
    ed[t] = d;
}

// ---------------- pass 1: denom[b][dst][h] += exp(leaky(es+ed)) ----------------
template<int H>
__global__ void edge_denom_kernel(const int* __restrict__ esrc, const int* __restrict__ edst,
                                  const float* __restrict__ es, const float* __restrict__ ed,
                                  float* __restrict__ den, int E) {
    int t = blockIdx.x * blockDim.x + threadIdx.x;
    if (t >= E * BATCH) return;
    int e = t % E;
    int b = t / E;
    int s = esrc[e], d = edst[e];
    const float* esp = es + ((size_t)b * N_NODES + s) * H;
    const float* edp = ed + ((size_t)b * N_NODES + d) * H;
    float* dnp = den + ((size_t)b * N_NODES + d) * H;
    #pragma unroll
    for (int h = 0; h < H; ++h) {
        float l = esp[h] + edp[h];
        l = l > 0.f ? l : 0.2f * l;
        atomicAdd(&dnp[h], __expf(l));
    }
}

// ---------------- pass 2: out[b][dst][h][u] += alpha * H[b][src][h][u] ----------------
// one 32-lane group per (e,b); lane = u
template<int H>
__global__ void edge_msg_kernel(const int* __restrict__ esrc, const int* __restrict__ edst,
                                const float* __restrict__ es, const float* __restrict__ ed,
                                const float* __restrict__ den, const float* __restrict__ Hf,
                                float* __restrict__ outAgg, int E) {
    int t = blockIdx.x * blockDim.x + threadIdx.x;
    int g = t / 32;
    int lane = t % 32;
    if (g >= E * BATCH) return;
    int e = g % E;
    int b = g / E;
    int s = esrc[e], d = edst[e];
    size_t srow = (size_t)b * N_NODES + s;
    size_t drow = (size_t)b * N_NODES + d;
    const float* esp = es + srow * H;
    const float* edp = ed + drow * H;
    const float* dnp = den + drow * H;
    const float* hp  = Hf + srow * (H * UNITS);
    float*       op  = outAgg + drow * (H * UNITS);
    #pragma unroll
    for (int h = 0; h < H; ++h) {
        float l = esp[h] + edp[h];
        l = l > 0.f ? l : 0.2f * l;
        float alpha = __expf(l) / (dnp[h] + 1e-9f);
        atomicAdd(&op[h * UNITS + lane], alpha * hp[h * UNITS + lane]);
    }
}

// ---------------- bias (+optional relu): dst[t] = f(src[t] + bias[t%C]) ----------------
__global__ void add_bias_kernel(const float* __restrict__ src, const float* __restrict__ bias,
                                float* __restrict__ dst, int total, int C, int doRelu) {
    int t = blockIdx.x * blockDim.x + threadIdx.x;
    if (t >= total) return;
    float x = src[t] + bias[t % C];
    dst[t] = doRelu ? fmaxf(x, 0.f) : x;
}

extern "C" void kernel_launch(void* const* d_in, const int* in_sizes, int n_in,
                              void* d_out, int out_size, void* d_ws, size_t ws_size,
                              hipStream_t stream) {
    const float* x    = (const float*)d_in[0];
    const int*   esrc = (const int*)d_in[1];
    const int*   edst = (const int*)d_in[2];
    const float* W1   = (const float*)d_in[3];
    const float* a1s  = (const float*)d_in[4];
    const float* a1d  = (const float*)d_in[5];
    const float* b1   = (const float*)d_in[6];
    const float* W2   = (const float*)d_in[7];
    const float* a2s  = (const float*)d_in[8];
    const float* a2d  = (const float*)d_in[9];
    const float* b2   = (const float*)d_in[10];
    float* out = (float*)d_out;
    const int E = in_sizes[1];
    const int rows = BATCH * N_NODES;  // 80000

    // workspace layout (floats)
    float* ws   = (float*)d_ws;
    float* h1   = ws;                              // rows*128
    float* out1 = h1 + (size_t)rows * 128;         // rows*128
    float* e1s  = out1 + (size_t)rows * 128;       // rows*4
    float* e1d  = e1s + (size_t)rows * NH1;        // rows*4
    float* den1 = e1d + (size_t)rows * NH1;        // rows*4
    // layer 2 reuses the h1 region (rows*67 < rows*128)
    float* h2   = h1;                              // rows*32
    float* e2s  = h2 + (size_t)rows * UNITS;       // rows
    float* e2d  = e2s + rows;                      // rows
    float* den2 = e2d + rows;                      // rows
    float* agg2 = den2 + rows;                     // rows*32

    const int TPB = 256;

    // ---------- layer 1 ----------
    hipMemsetAsync(out1, 0, (size_t)rows * 128 * sizeof(float), stream);
    hipMemsetAsync(den1, 0, (size_t)rows * NH1 * sizeof(float), stream);

    gemm_kernel<FIN, 128><<<(rows + 15) / 16, TPB, 0, stream>>>(x, W1, h1, rows);
    att_logits_kernel<NH1><<<(rows * NH1 + TPB - 1) / TPB, TPB, 0, stream>>>(
        h1, a1s, a1d, e1s, e1d, rows);
    edge_denom_kernel<NH1><<<(E * BATCH + TPB - 1) / TPB, TPB, 0, stream>>>(
        esrc, edst, e1s, e1d, den1, E);
    {
        long long threads = (long long)E * BATCH * 32;
        edge_msg_kernel<NH1><<<(int)((threads + TPB - 1) / TPB), TPB, 0, stream>>>(
            esrc, edst, e1s, e1d, den1, h1, out1, E);
    }
    add_bias_kernel<<<(rows * 128 + TPB - 1) / TPB, TPB, 0, stream>>>(
        out1, b1, out1, rows * 128, 128, 1);

    // ---------- layer 2 ----------
    hipMemsetAsync(den2, 0, (size_t)rows * sizeof(float), stream);
    hipMemsetAsync(agg2, 0, (size_t)rows * UNITS * sizeof(float), stream);

    gemm_kernel<128, UNITS><<<(rows + 15) / 16, TPB, 0, stream>>>(out1, W2, h2, rows);
    att_logits_kernel<1><<<(rows + TPB - 1) / TPB, TPB, 0, stream>>>(
        h2, a2s, a2d, e2s, e2d, rows);
    edge_denom_kernel<1><<<(E * BATCH + TPB - 1) / TPB, TPB, 0, stream>>>(
        esrc, edst, e2s, e2d, den2, E);
    {
        long long threads = (long long)E * BATCH * 32;
        edge_msg_kernel<1><<<(int)((threads + TPB - 1) / TPB), TPB, 0, stream>>>(
            esrc, edst, e2s, e2d, den2, h2, agg2, E);
    }
    add_bias_kernel<<<(rows * UNITS + TPB - 1) / TPB, TPB, 0, stream>>>(
        agg2, b2, out, rows * UNITS, UNITS, 0);
}

// Round 2
// 731.729 us; speedup vs baseline: 3.3142x; 3.3142x over previous
//
#include <hip/hip_runtime.h>

#define N_NODES 10000
#define BATCH 8
#define FIN 128
#define UNITS 32
#define NH1 4

// ---------------- GEMM: Hout[row][c] = sum_k X[row][k] * W[k][c] ----------------
template<int K, int COLS>
__global__ void gemm_kernel(const float* __restrict__ X, const float* __restrict__ W,
                            float* __restrict__ Hout, int rows) {
    __shared__ float Ws[K * COLS];
    int tid = threadIdx.x;
    for (int i = tid; i < K * COLS; i += blockDim.x) Ws[i] = W[i];
    __syncthreads();
    const int ROWS_PER_BLOCK = 16;
    int c  = tid % COLS;
    int rg = tid / COLS;
    int rstride = blockDim.x / COLS;
    int row0 = blockIdx.x * ROWS_PER_BLOCK;
    for (int r = rg; r < ROWS_PER_BLOCK; r += rstride) {
        int row = row0 + r;
        if (row >= rows) break;
        const float4* xr4 = (const float4*)(X + (size_t)row * K);
        float acc = 0.f;
        #pragma unroll
        for (int k4 = 0; k4 < K / 4; ++k4) {
            float4 xv = xr4[k4];
            acc += xv.x * Ws[(4*k4+0)*COLS + c];
            acc += xv.y * Ws[(4*k4+1)*COLS + c];
            acc += xv.z * Ws[(4*k4+2)*COLS + c];
            acc += xv.w * Ws[(4*k4+3)*COLS + c];
        }
        Hout[(size_t)row * COLS + c] = acc;
    }
}

// ---------------- attention logits ----------------
template<int H>
__global__ void att_logits_kernel(const float* __restrict__ Hf,
                                  const float* __restrict__ a_src,
                                  const float* __restrict__ a_dst,
                                  float* __restrict__ es, float* __restrict__ ed,
                                  int rows) {
    int t = blockIdx.x * blockDim.x + threadIdx.x;
    if (t >= rows * H) return;
    int row = t / H, h = t % H;
    const float4* hv = (const float4*)(Hf + (size_t)row * (H * UNITS) + h * UNITS);
    const float4* as = (const float4*)(a_src + h * UNITS);
    const float4* ad = (const float4*)(a_dst + h * UNITS);
    float s = 0.f, d = 0.f;
    #pragma unroll
    for (int i = 0; i < UNITS / 4; ++i) {
        float4 x = hv[i], A = as[i], D = ad[i];
        s += x.x*A.x + x.y*A.y + x.z*A.z + x.w*A.w;
        d += x.x*D.x + x.y*D.y + x.z*D.z + x.w*D.w;
    }
    es[t] = s;
    ed[t] = d;
}

// ---------------- CSR build ----------------
__global__ void deg_kernel(const int* __restrict__ edst, int* __restrict__ deg, int E) {
    int e = blockIdx.x * blockDim.x + threadIdx.x;
    if (e < E) atomicAdd(&deg[edst[e]], 1);
}

// single-block exclusive scan deg[N] -> row_ptr[N+1]
__global__ void scan_kernel(const int* __restrict__ deg, int* __restrict__ row_ptr, int N) {
    __shared__ int buf[1024];
    __shared__ int running_s;
    int tid = threadIdx.x;
    if (tid == 0) running_s = 0;
    __syncthreads();
    for (int base = 0; base < N; base += 1024) {
        int i = base + tid;
        int v = (i < N) ? deg[i] : 0;
        buf[tid] = v;
        __syncthreads();
        for (int off = 1; off < 1024; off <<= 1) {
            int t = (tid >= off) ? buf[tid - off] : 0;
            __syncthreads();
            buf[tid] += t;
            __syncthreads();
        }
        int incl = buf[tid];
        if (i < N) row_ptr[i] = running_s + incl - v;
        __syncthreads();
        if (tid == 1023) running_s += buf[1023];
        __syncthreads();
    }
    if (tid == 0) row_ptr[N] = running_s;
}

__global__ void scatter_kernel(const int* __restrict__ esrc, const int* __restrict__ edst,
                               const int* __restrict__ row_ptr, int* __restrict__ cursor,
                               int* __restrict__ col, int E) {
    int e = blockIdx.x * blockDim.x + threadIdx.x;
    if (e >= E) return;
    int d = edst[e];
    int pos = atomicAdd(&cursor[d], 1);
    col[row_ptr[d] + pos] = esrc[e];
}

// ---------------- layer-1 aggregation: one wave per (b, dst), 8 waves/block ----------
// es/ed layout: [b*N + node][4]. Hf: [b*N + node][128]. out: relu(agg + bias).
__global__ __launch_bounds__(512)
void agg1_kernel(const int* __restrict__ row_ptr, const int* __restrict__ col,
                 const float* __restrict__ es, const float* __restrict__ ed,
                 const float* __restrict__ Hf, const float* __restrict__ bias,
                 float* __restrict__ outF) {
    int d = blockIdx.x;
    int b = threadIdx.x >> 6;
    int lane = threadIdx.x & 63;
    int start = row_ptr[d], end = row_ptr[d + 1];
    size_t brow = (size_t)b * N_NODES;
    size_t drow = brow + d;
    float4 ed4 = ((const float4*)ed)[drow];
    // phase 1: denominators (4 heads)
    float dx = 0.f, dy = 0.f, dz = 0.f, dw = 0.f;
    for (int i = start + lane; i < end; i += 64) {
        int s = col[i];
        float4 e4 = ((const float4*)es)[brow + s];
        float l;
        l = e4.x + ed4.x; l = l > 0.f ? l : 0.2f * l; dx += __expf(l);
        l = e4.y + ed4.y; l = l > 0.f ? l : 0.2f * l; dy += __expf(l);
        l = e4.z + ed4.z; l = l > 0.f ? l : 0.2f * l; dz += __expf(l);
        l = e4.w + ed4.w; l = l > 0.f ? l : 0.2f * l; dw += __expf(l);
    }
    #pragma unroll
    for (int off = 32; off; off >>= 1) {
        dx += __shfl_xor(dx, off);
        dy += __shfl_xor(dy, off);
        dz += __shfl_xor(dz, off);
        dw += __shfl_xor(dw, off);
    }
    float ix = 1.f / (dx + 1e-9f);
    float iy = 1.f / (dy + 1e-9f);
    float iz = 1.f / (dz + 1e-9f);
    float iw = 1.f / (dw + 1e-9f);
    // phase 2: gather-accumulate. lane owns cols lane and lane+64.
    float acc0 = 0.f, acc1 = 0.f;
    int hiSel = lane & 32;
    for (int i = start; i < end; ++i) {
        int s = col[i];
        size_t srow = brow + s;
        float4 e4 = ((const float4*)es)[srow];   // broadcast load
        float l, a0, a1, a2, a3;
        l = e4.x + ed4.x; l = l > 0.f ? l : 0.2f * l; a0 = __expf(l) * ix;
        l = e4.y + ed4.y; l = l > 0.f ? l : 0.2f * l; a1 = __expf(l) * iy;
        l = e4.z + ed4.z; l = l > 0.f ? l : 0.2f * l; a2 = __expf(l) * iz;
        l = e4.w + ed4.w; l = l > 0.f ? l : 0.2f * l; a3 = __expf(l) * iw;
        float alphaLo = hiSel ? a1 : a0;   // col = lane      -> head lane>>5
        float alphaHi = hiSel ? a3 : a2;   // col = lane+64   -> head 2+(lane>>5)
        const float* hp = Hf + srow * 128;
        acc0 += alphaLo * hp[lane];
        acc1 += alphaHi * hp[lane + 64];
    }
    float v0 = fmaxf(acc0 + bias[lane], 0.f);
    float v1 = fmaxf(acc1 + bias[lane + 64], 0.f);
    float* op = outF + drow * 128;
    op[lane] = v0;
    op[lane + 64] = v1;
}

// ---------------- layer-2 aggregation: one wave per (b, dst); 2 edges in flight ------
__global__ __launch_bounds__(512)
void agg2_kernel(const int* __restrict__ row_ptr, const int* __restrict__ col,
                 const float* __restrict__ es, const float* __restrict__ ed,
                 const float* __restrict__ Hf, const float* __restrict__ bias,
                 float* __restrict__ outF) {
    int d = blockIdx.x;
    int b = threadIdx.x >> 6;
    int lane = threadIdx.x & 63;
    int sub = lane >> 5;
    int c = lane & 31;
    int start = row_ptr[d], end = row_ptr[d + 1];
    size_t brow = (size_t)b * N_NODES;
    size_t drow = brow + d;
    float edv = ed[drow];
    float den = 0.f;
    for (int i = start + lane; i < end; i += 64) {
        float l = es[brow + col[i]] + edv;
        l = l > 0.f ? l : 0.2f * l;
        den += __expf(l);
    }
    #pragma unroll
    for (int off = 32; off; off >>= 1) den += __shfl_xor(den, off);
    float invden = 1.f / (den + 1e-9f);
    float acc = 0.f;
    for (int i = start + sub; i < end; i += 2) {
        int s = col[i];
        size_t srow = brow + s;
        float l = es[srow] + edv;
        l = l > 0.f ? l : 0.2f * l;
        float alpha = __expf(l) * invden;
        acc += alpha * Hf[srow * 32 + c];
    }
    acc += __shfl_xor(acc, 32);
    if (sub == 0) outF[drow * 32 + c] = acc + bias[c];
}

extern "C" void kernel_launch(void* const* d_in, const int* in_sizes, int n_in,
                              void* d_out, int out_size, void* d_ws, size_t ws_size,
                              hipStream_t stream) {
    const float* x    = (const float*)d_in[0];
    const int*   esrc = (const int*)d_in[1];
    const int*   edst = (const int*)d_in[2];
    const float* W1   = (const float*)d_in[3];
    const float* a1s  = (const float*)d_in[4];
    const float* a1d  = (const float*)d_in[5];
    const float* b1   = (const float*)d_in[6];
    const float* W2   = (const float*)d_in[7];
    const float* a2s  = (const float*)d_in[8];
    const float* a2d  = (const float*)d_in[9];
    const float* b2   = (const float*)d_in[10];
    float* out = (float*)d_out;
    const int E = in_sizes[1];
    const int rows = BATCH * N_NODES;  // 80000

    // workspace layout (floats)
    float* ws   = (float*)d_ws;
    float* h1   = ws;                              // rows*128
    float* out1 = h1 + (size_t)rows * 128;         // rows*128
    float* e1s  = out1 + (size_t)rows * 128;       // rows*4
    float* e1d  = e1s + (size_t)rows * NH1;        // rows*4
    // layer 2 reuses h1 region
    float* h2   = h1;                              // rows*32
    float* e2s  = h2 + (size_t)rows * UNITS;       // rows
    float* e2d  = e2s + rows;                      // rows
    // CSR (int) region after e1d
    int* deg     = (int*)(e1d + (size_t)rows * NH1);  // N
    int* cursor  = deg + N_NODES;                     // N
    int* row_ptr = cursor + N_NODES;                  // N+1
    int* colIdx  = row_ptr + N_NODES + 1;             // E

    const int TPB = 256;

    // ---------- CSR build (shared by both layers) ----------
    hipMemsetAsync(deg, 0, N_NODES * sizeof(int), stream);
    hipMemsetAsync(cursor, 0, N_NODES * sizeof(int), stream);
    deg_kernel<<<(E + TPB - 1) / TPB, TPB, 0, stream>>>(edst, deg, E);
    scan_kernel<<<1, 1024, 0, stream>>>(deg, row_ptr, N_NODES);
    scatter_kernel<<<(E + TPB - 1) / TPB, TPB, 0, stream>>>(esrc, edst, row_ptr, cursor, colIdx, E);

    // ---------- layer 1 ----------
    gemm_kernel<FIN, 128><<<(rows + 15) / 16, TPB, 0, stream>>>(x, W1, h1, rows);
    att_logits_kernel<NH1><<<(rows * NH1 + TPB - 1) / TPB, TPB, 0, stream>>>(
        h1, a1s, a1d, e1s, e1d, rows);
    agg1_kernel<<<N_NODES, 512, 0, stream>>>(row_ptr, colIdx, e1s, e1d, h1, b1, out1);

    // ---------- layer 2 ----------
    gemm_kernel<128, UNITS><<<(rows + 15) / 16, TPB, 0, stream>>>(out1, W2, h2, rows);
    att_logits_kernel<1><<<(rows + TPB - 1) / TPB, TPB, 0, stream>>>(
        h2, a2s, a2d, e2s, e2d, rows);
    agg2_kernel<<<N_NODES, 512, 0, stream>>>(row_ptr, colIdx, e2s, e2d, h2, b2, out);
}

// Round 3
// 509.478 us; speedup vs baseline: 4.7600x; 1.4362x over previous
//
#include <hip/hip_runtime.h>

#define N_NODES 10000
#define BATCH 8
#define FIN 128
#define UNITS 32
#define NH1 4

// ---------------- register-tiled GEMM: Hout[row][c] = sum_k X[row][k]*W[k][c] ------
// 4x4 outputs per thread; K chunked by KC; X staged transposed in LDS.
template<int K, int COLS, int BM, int KC>
__global__ __launch_bounds__((BM / 4) * (COLS / 4))
void gemm_tiled(const float* __restrict__ X, const float* __restrict__ W,
                float* __restrict__ Hout, int rows) {
    constexpr int TM = 4, TN = 4;
    constexpr int NCG = COLS / TN;
    constexpr int NRG = BM / TM;
    constexpr int NT = NCG * NRG;          // threads per block
    constexpr int XPAD = BM + 4;           // keep 16B alignment, break bank stride
    __shared__ float Xs[KC][XPAD];
    __shared__ float Ws[KC][COLS];
    const int tid = threadIdx.x;
    const int cg = tid % NCG;
    const int rg = tid / NCG;
    const int row0 = blockIdx.x * BM;
    float acc[TM][TN] = {};
    for (int k0 = 0; k0 < K; k0 += KC) {
        // stage W chunk [KC][COLS] (row-major contiguous)
        const float4* wsrc = (const float4*)(W + (size_t)k0 * COLS);
        float4* wdst = (float4*)&Ws[0][0];
        #pragma unroll
        for (int idx = tid; idx < KC * COLS / 4; idx += NT) wdst[idx] = wsrc[idx];
        // stage X chunk transposed: Xs[k][row]
        constexpr int F4R = KC / 4;
        #pragma unroll
        for (int idx = tid; idx < BM * F4R; idx += NT) {
            int row = idx / F4R, k4 = idx % F4R;
            float4 v = *(const float4*)(X + (size_t)(row0 + row) * K + k0 + 4 * k4);
            Xs[4 * k4 + 0][row] = v.x;
            Xs[4 * k4 + 1][row] = v.y;
            Xs[4 * k4 + 2][row] = v.z;
            Xs[4 * k4 + 3][row] = v.w;
        }
        __syncthreads();
        #pragma unroll
        for (int k = 0; k < KC; ++k) {
            float wr[TN], xr[TM];
            *(float4*)wr = *(const float4*)&Ws[k][TN * cg];
            *(float4*)xr = *(const float4*)&Xs[k][TM * rg];
            #pragma unroll
            for (int i = 0; i < TM; ++i)
                #pragma unroll
                for (int j = 0; j < TN; ++j)
                    acc[i][j] += xr[i] * wr[j];
        }
        __syncthreads();
    }
    #pragma unroll
    for (int i = 0; i < TM; ++i) {
        int row = row0 + TM * rg + i;
        if (row < rows)
            *(float4*)(Hout + (size_t)row * COLS + TN * cg) = *(float4*)acc[i];
    }
}

// ---------------- attention logits ----------------
template<int H>
__global__ void att_logits_kernel(const float* __restrict__ Hf,
                                  const float* __restrict__ a_src,
                                  const float* __restrict__ a_dst,
                                  float* __restrict__ es, float* __restrict__ ed,
                                  int rows) {
    int t = blockIdx.x * blockDim.x + threadIdx.x;
    if (t >= rows * H) return;
    int row = t / H, h = t % H;
    const float4* hv = (const float4*)(Hf + (size_t)row * (H * UNITS) + h * UNITS);
    const float4* as = (const float4*)(a_src + h * UNITS);
    const float4* ad = (const float4*)(a_dst + h * UNITS);
    float s = 0.f, d = 0.f;
    #pragma unroll
    for (int i = 0; i < UNITS / 4; ++i) {
        float4 x = hv[i], A = as[i], D = ad[i];
        s += x.x*A.x + x.y*A.y + x.z*A.z + x.w*A.w;
        d += x.x*D.x + x.y*D.y + x.z*D.z + x.w*D.w;
    }
    es[t] = s;
    ed[t] = d;
}

// ---------------- CSR build ----------------
__global__ void deg_kernel(const int* __restrict__ edst, int* __restrict__ deg, int E) {
    int e = blockIdx.x * blockDim.x + threadIdx.x;
    if (e < E) atomicAdd(&deg[edst[e]], 1);
}

__global__ void scan_kernel(const int* __restrict__ deg, int* __restrict__ row_ptr, int N) {
    __shared__ int buf[1024];
    __shared__ int running_s;
    int tid = threadIdx.x;
    if (tid == 0) running_s = 0;
    __syncthreads();
    for (int base = 0; base < N; base += 1024) {
        int i = base + tid;
        int v = (i < N) ? deg[i] : 0;
        buf[tid] = v;
        __syncthreads();
        for (int off = 1; off < 1024; off <<= 1) {
            int t = (tid >= off) ? buf[tid - off] : 0;
            __syncthreads();
            buf[tid] += t;
            __syncthreads();
        }
        int incl = buf[tid];
        if (i < N) row_ptr[i] = running_s + incl - v;
        __syncthreads();
        if (tid == 1023) running_s += buf[1023];
        __syncthreads();
    }
    if (tid == 0) row_ptr[N] = running_s;
}

__global__ void scatter_kernel(const int* __restrict__ esrc, const int* __restrict__ edst,
                               const int* __restrict__ row_ptr, int* __restrict__ cursor,
                               int* __restrict__ col, int E) {
    int e = blockIdx.x * blockDim.x + threadIdx.x;
    if (e >= E) return;
    int d = edst[e];
    int pos = atomicAdd(&cursor[d], 1);
    col[row_ptr[d] + pos] = esrc[e];
}

// ---------------- layer-1 aggregation: one wave per (b, dst), 8 waves/block ----------
__global__ __launch_bounds__(512)
void agg1_kernel(const int* __restrict__ row_ptr, const int* __restrict__ col,
                 const float* __restrict__ es, const float* __restrict__ ed,
                 const float* __restrict__ Hf, const float* __restrict__ bias,
                 float* __restrict__ outF) {
    int d = blockIdx.x;
    int b = threadIdx.x >> 6;
    int lane = threadIdx.x & 63;
    int start = row_ptr[d], end = row_ptr[d + 1];
    size_t brow = (size_t)b * N_NODES;
    size_t drow = brow + d;
    float4 ed4 = ((const float4*)ed)[drow];
    float dx = 0.f, dy = 0.f, dz = 0.f, dw = 0.f;
    for (int i = start + lane; i < end; i += 64) {
        int s = col[i];
        float4 e4 = ((const float4*)es)[brow + s];
        float l;
        l = e4.x + ed4.x; l = l > 0.f ? l : 0.2f * l; dx += __expf(l);
        l = e4.y + ed4.y; l = l > 0.f ? l : 0.2f * l; dy += __expf(l);
        l = e4.z + ed4.z; l = l > 0.f ? l : 0.2f * l; dz += __expf(l);
        l = e4.w + ed4.w; l = l > 0.f ? l : 0.2f * l; dw += __expf(l);
    }
    #pragma unroll
    for (int off = 32; off; off >>= 1) {
        dx += __shfl_xor(dx, off);
        dy += __shfl_xor(dy, off);
        dz += __shfl_xor(dz, off);
        dw += __shfl_xor(dw, off);
    }
    float ix = 1.f / (dx + 1e-9f);
    float iy = 1.f / (dy + 1e-9f);
    float iz = 1.f / (dz + 1e-9f);
    float iw = 1.f / (dw + 1e-9f);
    float acc0 = 0.f, acc1 = 0.f;
    int hiSel = lane & 32;
    for (int i = start; i < end; ++i) {
        int s = col[i];
        size_t srow = brow + s;
        float4 e4 = ((const float4*)es)[srow];
        float l, a0, a1, a2, a3;
        l = e4.x + ed4.x; l = l > 0.f ? l : 0.2f * l; a0 = __expf(l) * ix;
        l = e4.y + ed4.y; l = l > 0.f ? l : 0.2f * l; a1 = __expf(l) * iy;
        l = e4.z + ed4.z; l = l > 0.f ? l : 0.2f * l; a2 = __expf(l) * iz;
        l = e4.w + ed4.w; l = l > 0.f ? l : 0.2f * l; a3 = __expf(l) * iw;
        float alphaLo = hiSel ? a1 : a0;
        float alphaHi = hiSel ? a3 : a2;
        const float* hp = Hf + srow * 128;
        acc0 += alphaLo * hp[lane];
        acc1 += alphaHi * hp[lane + 64];
    }
    float v0 = fmaxf(acc0 + bias[lane], 0.f);
    float v1 = fmaxf(acc1 + bias[lane + 64], 0.f);
    float* op = outF + drow * 128;
    op[lane] = v0;
    op[lane + 64] = v1;
}

// ---------------- layer-2 aggregation ----------------
__global__ __launch_bounds__(512)
void agg2_kernel(const int* __restrict__ row_ptr, const int* __restrict__ col,
                 const float* __restrict__ es, const float* __restrict__ ed,
                 const float* __restrict__ Hf, const float* __restrict__ bias,
                 float* __restrict__ outF) {
    int d = blockIdx.x;
    int b = threadIdx.x >> 6;
    int lane = threadIdx.x & 63;
    int sub = lane >> 5;
    int c = lane & 31;
    int start = row_ptr[d], end = row_ptr[d + 1];
    size_t brow = (size_t)b * N_NODES;
    size_t drow = brow + d;
    float edv = ed[drow];
    float den = 0.f;
    for (int i = start + lane; i < end; i += 64) {
        float l = es[brow + col[i]] + edv;
        l = l > 0.f ? l : 0.2f * l;
        den += __expf(l);
    }
    #pragma unroll
    for (int off = 32; off; off >>= 1) den += __shfl_xor(den, off);
    float invden = 1.f / (den + 1e-9f);
    float acc = 0.f;
    for (int i = start + sub; i < end; i += 2) {
        int s = col[i];
        size_t srow = brow + s;
        float l = es[srow] + edv;
        l = l > 0.f ? l : 0.2f * l;
        float alpha = __expf(l) * invden;
        acc += alpha * Hf[srow * 32 + c];
    }
    acc += __shfl_xor(acc, 32);
    if (sub == 0) outF[drow * 32 + c] = acc + bias[c];
}

extern "C" void kernel_launch(void* const* d_in, const int* in_sizes, int n_in,
                              void* d_out, int out_size, void* d_ws, size_t ws_size,
                              hipStream_t stream) {
    const float* x    = (const float*)d_in[0];
    const int*   esrc = (const int*)d_in[1];
    const int*   edst = (const int*)d_in[2];
    const float* W1   = (const float*)d_in[3];
    const float* a1s  = (const float*)d_in[4];
    const float* a1d  = (const float*)d_in[5];
    const float* b1   = (const float*)d_in[6];
    const float* W2   = (const float*)d_in[7];
    const float* a2s  = (const float*)d_in[8];
    const float* a2d  = (const float*)d_in[9];
    const float* b2   = (const float*)d_in[10];
    float* out = (float*)d_out;
    const int E = in_sizes[1];
    const int rows = BATCH * N_NODES;  // 80000

    // workspace layout (floats)
    float* ws   = (float*)d_ws;
    float* h1   = ws;                              // rows*128
    float* out1 = h1 + (size_t)rows * 128;         // rows*128
    float* e1s  = out1 + (size_t)rows * 128;       // rows*4
    float* e1d  = e1s + (size_t)rows * NH1;        // rows*4
    // layer 2 reuses h1 region
    float* h2   = h1;                              // rows*32
    float* e2s  = h2 + (size_t)rows * UNITS;       // rows
    float* e2d  = e2s + rows;                      // rows
    // CSR (int) region after e1d
    int* deg     = (int*)(e1d + (size_t)rows * NH1);  // N
    int* cursor  = deg + N_NODES;                     // N
    int* row_ptr = cursor + N_NODES;                  // N+1
    int* colIdx  = row_ptr + N_NODES + 1;             // E

    const int TPB = 256;

    // ---------- CSR build (shared by both layers) ----------
    hipMemsetAsync(deg, 0, N_NODES * sizeof(int), stream);
    hipMemsetAsync(cursor, 0, N_NODES * sizeof(int), stream);
    deg_kernel<<<(E + TPB - 1) / TPB, TPB, 0, stream>>>(edst, deg, E);
    scan_kernel<<<1, 1024, 0, stream>>>(deg, row_ptr, N_NODES);
    scatter_kernel<<<(E + TPB - 1) / TPB, TPB, 0, stream>>>(esrc, edst, row_ptr, cursor, colIdx, E);

    // ---------- layer 1 ----------
    gemm_tiled<FIN, 128, 32, 32><<<rows / 32, 256, 0, stream>>>(x, W1, h1, rows);
    att_logits_kernel<NH1><<<(rows * NH1 + TPB - 1) / TPB, TPB, 0, stream>>>(
        h1, a1s, a1d, e1s, e1d, rows);
    agg1_kernel<<<N_NODES, 512, 0, stream>>>(row_ptr, colIdx, e1s, e1d, h1, b1, out1);

    // ---------- layer 2 ----------
    gemm_tiled<128, UNITS, 128, 32><<<rows / 128, 256, 0, stream>>>(out1, W2, h2, rows);
    att_logits_kernel<1><<<(rows + TPB - 1) / TPB, TPB, 0, stream>>>(
        h2, a2s, a2d, e2s, e2d, rows);
    agg2_kernel<<<N_NODES, 512, 0, stream>>>(row_ptr, colIdx, e2s, e2d, h2, b2, out);
}

// Round 4
// 344.355 us; speedup vs baseline: 7.0425x; 1.4795x over previous
//
#include <hip/hip_runtime.h>
#include <hip/hip_fp16.h>

#define N_NODES 10000
#define BATCH 8
#define FIN 128
#define UNITS 32
#define NH1 4

// ---------------- register-tiled GEMM: Hout[row][c] = sum_k X[row][k]*W[k][c] ------
// 4x4 outputs per thread; K chunked by KC; X staged transposed in LDS. Output f16.
template<int K, int COLS, int BM, int KC>
__global__ __launch_bounds__((BM / 4) * (COLS / 4))
void gemm_tiled_h(const float* __restrict__ X, const float* __restrict__ W,
                  __half* __restrict__ Hout, int rows) {
    constexpr int TM = 4, TN = 4;
    constexpr int NCG = COLS / TN;
    constexpr int NRG = BM / TM;
    constexpr int NT = NCG * NRG;
    constexpr int XPAD = BM + 4;
    __shared__ float Xs[KC][XPAD];
    __shared__ float Ws[KC][COLS];
    const int tid = threadIdx.x;
    const int cg = tid % NCG;
    const int rg = tid / NCG;
    const int row0 = blockIdx.x * BM;
    float acc[TM][TN] = {};
    for (int k0 = 0; k0 < K; k0 += KC) {
        const float4* wsrc = (const float4*)(W + (size_t)k0 * COLS);
        float4* wdst = (float4*)&Ws[0][0];
        #pragma unroll
        for (int idx = tid; idx < KC * COLS / 4; idx += NT) wdst[idx] = wsrc[idx];
        constexpr int F4R = KC / 4;
        #pragma unroll
        for (int idx = tid; idx < BM * F4R; idx += NT) {
            int row = idx / F4R, k4 = idx % F4R;
            float4 v = *(const float4*)(X + (size_t)(row0 + row) * K + k0 + 4 * k4);
            Xs[4 * k4 + 0][row] = v.x;
            Xs[4 * k4 + 1][row] = v.y;
            Xs[4 * k4 + 2][row] = v.z;
            Xs[4 * k4 + 3][row] = v.w;
        }
        __syncthreads();
        #pragma unroll
        for (int k = 0; k < KC; ++k) {
            float wr[TN], xr[TM];
            *(float4*)wr = *(const float4*)&Ws[k][TN * cg];
            *(float4*)xr = *(const float4*)&Xs[k][TM * rg];
            #pragma unroll
            for (int i = 0; i < TM; ++i)
                #pragma unroll
                for (int j = 0; j < TN; ++j)
                    acc[i][j] += xr[i] * wr[j];
        }
        __syncthreads();
    }
    #pragma unroll
    for (int i = 0; i < TM; ++i) {
        int row = row0 + TM * rg + i;
        if (row < rows) {
            __half2 h01 = __floats2half2_rn(acc[i][0], acc[i][1]);
            __half2 h23 = __floats2half2_rn(acc[i][2], acc[i][3]);
            uint2 pk;
            pk.x = *reinterpret_cast<unsigned int*>(&h01);
            pk.y = *reinterpret_cast<unsigned int*>(&h23);
            *reinterpret_cast<uint2*>(Hout + (size_t)row * COLS + TN * cg) = pk;
        }
    }
}

// ---------------- attention logits from f16 features ----------------
template<int H>
__global__ void att_logits_h(const __half* __restrict__ Hf,
                             const float* __restrict__ a_src,
                             const float* __restrict__ a_dst,
                             float* __restrict__ es, float* __restrict__ ed,
                             int rows) {
    int t = blockIdx.x * blockDim.x + threadIdx.x;
    if (t >= rows * H) return;
    int row = t / H, h = t % H;
    const __half2* hv = (const __half2*)(Hf + (size_t)row * (H * UNITS) + h * UNITS);
    const float* as = a_src + h * UNITS;
    const float* ad = a_dst + h * UNITS;
    float s = 0.f, d = 0.f;
    #pragma unroll
    for (int i = 0; i < UNITS / 2; ++i) {
        float2 xv = __half22float2(hv[i]);
        s += xv.x * as[2 * i] + xv.y * as[2 * i + 1];
        d += xv.x * ad[2 * i] + xv.y * ad[2 * i + 1];
    }
    es[t] = s;
    ed[t] = d;
}

// ---------------- CSR build ----------------
__global__ void deg_kernel(const int* __restrict__ edst, int* __restrict__ deg, int E) {
    int e = blockIdx.x * blockDim.x + threadIdx.x;
    if (e < E) atomicAdd(&deg[edst[e]], 1);
}

__global__ void scan_kernel(const int* __restrict__ deg, int* __restrict__ row_ptr, int N) {
    __shared__ int buf[1024];
    __shared__ int running_s;
    int tid = threadIdx.x;
    if (tid == 0) running_s = 0;
    __syncthreads();
    for (int base = 0; base < N; base += 1024) {
        int i = base + tid;
        int v = (i < N) ? deg[i] : 0;
        buf[tid] = v;
        __syncthreads();
        for (int off = 1; off < 1024; off <<= 1) {
            int t = (tid >= off) ? buf[tid - off] : 0;
            __syncthreads();
            buf[tid] += t;
            __syncthreads();
        }
        int incl = buf[tid];
        if (i < N) row_ptr[i] = running_s + incl - v;
        __syncthreads();
        if (tid == 1023) running_s += buf[1023];
        __syncthreads();
    }
    if (tid == 0) row_ptr[N] = running_s;
}

__global__ void scatter_kernel(const int* __restrict__ esrc, const int* __restrict__ edst,
                               const int* __restrict__ row_ptr, int* __restrict__ cursor,
                               int* __restrict__ col, int E) {
    int e = blockIdx.x * blockDim.x + threadIdx.x;
    if (e >= E) return;
    int d = edst[e];
    int pos = atomicAdd(&cursor[d], 1);
    col[row_ptr[d] + pos] = esrc[e];
}

// ---------------- layer-1 aggregation: one wave per (b, dst), 8 waves/block ----------
// Chunked: lanes compute 64 edges' alphas in parallel into LDS, then serial accumulate.
__global__ __launch_bounds__(512)
void agg1_kernel(const int* __restrict__ row_ptr, const int* __restrict__ col,
                 const float* __restrict__ es, const float* __restrict__ ed,
                 const __half* __restrict__ Hf, const float* __restrict__ bias,
                 float* __restrict__ outF) {
    __shared__ float evS[8][64][4];   // 32 KB: alphas per wave per chunk-edge
    __shared__ int colS[64];
    int d = blockIdx.x;
    int b = threadIdx.x >> 6;
    int lane = threadIdx.x & 63;
    int start = row_ptr[d], end = row_ptr[d + 1];
    size_t brow = (size_t)b * N_NODES;
    size_t drow = brow + d;
    float4 ed4 = ((const float4*)ed)[drow];
    // phase 1: denominators (4 heads), lane-parallel over edges
    float dx = 0.f, dy = 0.f, dz = 0.f, dw = 0.f;
    for (int i = start + lane; i < end; i += 64) {
        int s = col[i];
        float4 e4 = ((const float4*)es)[brow + s];
        float l;
        l = e4.x + ed4.x; l = l > 0.f ? l : 0.2f * l; dx += __expf(l);
        l = e4.y + ed4.y; l = l > 0.f ? l : 0.2f * l; dy += __expf(l);
        l = e4.z + ed4.z; l = l > 0.f ? l : 0.2f * l; dz += __expf(l);
        l = e4.w + ed4.w; l = l > 0.f ? l : 0.2f * l; dw += __expf(l);
    }
    #pragma unroll
    for (int off = 32; off; off >>= 1) {
        dx += __shfl_xor(dx, off);
        dy += __shfl_xor(dy, off);
        dz += __shfl_xor(dz, off);
        dw += __shfl_xor(dw, off);
    }
    float ix = 1.f / (dx + 1e-9f);
    float iy = 1.f / (dy + 1e-9f);
    float iz = 1.f / (dz + 1e-9f);
    float iw = 1.f / (dw + 1e-9f);
    // phase 2: chunked gather-accumulate. lane owns cols lane and lane+64.
    float acc0 = 0.f, acc1 = 0.f;
    int hiSel = lane & 32;
    for (int i0 = start; i0 < end; i0 += 64) {
        int nch = end - i0; if (nch > 64) nch = 64;
        __syncthreads();   // protect LDS reuse (uniform trips: all waves share d)
        if (lane < nch) {
            int s = col[i0 + lane];
            if (b == 0) colS[lane] = s;
            float4 e4 = ((const float4*)es)[brow + s];
            float l, a0, a1, a2, a3;
            l = e4.x + ed4.x; l = l > 0.f ? l : 0.2f * l; a0 = __expf(l) * ix;
            l = e4.y + ed4.y; l = l > 0.f ? l : 0.2f * l; a1 = __expf(l) * iy;
            l = e4.z + ed4.z; l = l > 0.f ? l : 0.2f * l; a2 = __expf(l) * iz;
            l = e4.w + ed4.w; l = l > 0.f ? l : 0.2f * l; a3 = __expf(l) * iw;
            *(float4*)&evS[b][lane][0] = make_float4(a0, a1, a2, a3);
        }
        __syncthreads();
        for (int t = 0; t < nch; ++t) {
            int s = colS[t];
            float4 a = *(const float4*)&evS[b][t][0];   // LDS broadcast
            float alphaLo = hiSel ? a.y : a.x;
            float alphaHi = hiSel ? a.w : a.z;
            const __half* hp = Hf + ((size_t)brow + s) * 128;
            acc0 += alphaLo * __half2float(hp[lane]);
            acc1 += alphaHi * __half2float(hp[lane + 64]);
        }
    }
    float v0 = fmaxf(acc0 + bias[lane], 0.f);
    float v1 = fmaxf(acc1 + bias[lane + 64], 0.f);
    float* op = outF + drow * 128;
    op[lane] = v0;
    op[lane + 64] = v1;
}

// ---------------- layer-2 aggregation (chunked, f16 features) ----------------
__global__ __launch_bounds__(512)
void agg2_kernel(const int* __restrict__ row_ptr, const int* __restrict__ col,
                 const float* __restrict__ es, const float* __restrict__ ed,
                 const __half* __restrict__ Hf, const float* __restrict__ bias,
                 float* __restrict__ outF) {
    __shared__ float evS[8][64];   // 2 KB
    __shared__ int colS[64];
    int d = blockIdx.x;
    int b = threadIdx.x >> 6;
    int lane = threadIdx.x & 63;
    int sub = lane >> 5;
    int c = lane & 31;
    int start = row_ptr[d], end = row_ptr[d + 1];
    size_t brow = (size_t)b * N_NODES;
    size_t drow = brow + d;
    float edv = ed[drow];
    float den = 0.f;
    for (int i = start + lane; i < end; i += 64) {
        float l = es[brow + col[i]] + edv;
        l = l > 0.f ? l : 0.2f * l;
        den += __expf(l);
    }
    #pragma unroll
    for (int off = 32; off; off >>= 1) den += __shfl_xor(den, off);
    float invden = 1.f / (den + 1e-9f);
    float acc = 0.f;
    for (int i0 = start; i0 < end; i0 += 64) {
        int nch = end - i0; if (nch > 64) nch = 64;
        __syncthreads();
        if (lane < nch) {
            int s = col[i0 + lane];
            if (b == 0) colS[lane] = s;
            float l = es[brow + s] + edv;
            l = l > 0.f ? l : 0.2f * l;
            evS[b][lane] = __expf(l) * invden;
        }
        __syncthreads();
        for (int t = sub; t < nch; t += 2) {
            int s = colS[t];
            float alpha = evS[b][t];
            acc += alpha * __half2float(Hf[((size_t)brow + s) * 32 + c]);
        }
    }
    acc += __shfl_xor(acc, 32);
    if (sub == 0) outF[drow * 32 + c] = acc + bias[c];
}

extern "C" void kernel_launch(void* const* d_in, const int* in_sizes, int n_in,
                              void* d_out, int out_size, void* d_ws, size_t ws_size,
                              hipStream_t stream) {
    const float* x    = (const float*)d_in[0];
    const int*   esrc = (const int*)d_in[1];
    const int*   edst = (const int*)d_in[2];
    const float* W1   = (const float*)d_in[3];
    const float* a1s  = (const float*)d_in[4];
    const float* a1d  = (const float*)d_in[5];
    const float* b1   = (const float*)d_in[6];
    const float* W2   = (const float*)d_in[7];
    const float* a2s  = (const float*)d_in[8];
    const float* a2d  = (const float*)d_in[9];
    const float* b2   = (const float*)d_in[10];
    float* out = (float*)d_out;
    const int E = in_sizes[1];
    const int rows = BATCH * N_NODES;  // 80000

    // workspace layout (floats)
    float* ws   = (float*)d_ws;
    __half* h1h = (__half*)ws;                     // rows*128 halfs (fits rows*64 f32 slot)
    float* out1 = ws + (size_t)rows * 128;         // rows*128 f32
    float* e1s  = out1 + (size_t)rows * 128;       // rows*4
    float* e1d  = e1s + (size_t)rows * NH1;        // rows*4
    // layer 2 reuse
    __half* h2h = (__half*)ws;                     // rows*32 halfs (h1h dead after agg1)
    float* e2s  = e1s;                             // rows (e1s dead after agg1)
    float* e2d  = e1s + rows;                      // rows
    // CSR (int) region after e1d
    int* deg     = (int*)(e1d + (size_t)rows * NH1);  // N
    int* cursor  = deg + N_NODES;                     // N
    int* row_ptr = cursor + N_NODES;                  // N+1
    int* colIdx  = row_ptr + N_NODES + 1;             // E

    const int TPB = 256;

    // ---------- CSR build (shared by both layers) ----------
    hipMemsetAsync(deg, 0, N_NODES * sizeof(int), stream);
    hipMemsetAsync(cursor, 0, N_NODES * sizeof(int), stream);
    deg_kernel<<<(E + TPB - 1) / TPB, TPB, 0, stream>>>(edst, deg, E);
    scan_kernel<<<1, 1024, 0, stream>>>(deg, row_ptr, N_NODES);
    scatter_kernel<<<(E + TPB - 1) / TPB, TPB, 0, stream>>>(esrc, edst, row_ptr, cursor, colIdx, E);

    // ---------- layer 1 ----------
    gemm_tiled_h<FIN, 128, 32, 32><<<rows / 32, 256, 0, stream>>>(x, W1, h1h, rows);
    att_logits_h<NH1><<<(rows * NH1 + TPB - 1) / TPB, TPB, 0, stream>>>(
        h1h, a1s, a1d, e1s, e1d, rows);
    agg1_kernel<<<N_NODES, 512, 0, stream>>>(row_ptr, colIdx, e1s, e1d, h1h, b1, out1);

    // ---------- layer 2 ----------
    gemm_tiled_h<128, UNITS, 128, 32><<<rows / 128, 256, 0, stream>>>(out1, W2, h2h, rows);
    att_logits_h<1><<<(rows + TPB - 1) / TPB, TPB, 0, stream>>>(
        h2h, a2s, a2d, e2s, e2d, rows);
    agg2_kernel<<<N_NODES, 512, 0, stream>>>(row_ptr, colIdx, e2s, e2d, h2h, b2, out);
}

// Round 5
// 303.321 us; speedup vs baseline: 7.9952x; 1.1353x over previous
//
#include <hip/hip_runtime.h>
#include <hip/hip_fp16.h>

#define N_NODES 10000
#define BATCH 8
#define FIN 128
#define UNITS 32
#define NH1 4

// ---------------- vec4 loader (f32 or f16 source) ----------------
template<typename T> struct Vec4Loader;
template<> struct Vec4Loader<float> {
    static __device__ inline float4 load(const float* p) { return *(const float4*)p; }
};
template<> struct Vec4Loader<__half> {
    static __device__ inline float4 load(const __half* p) {
        const __half2* p2 = (const __half2*)p;
        float2 a = __half22float2(p2[0]);
        float2 b = __half22float2(p2[1]);
        return make_float4(a.x, a.y, b.x, b.y);
    }
};

// ---------------- register-tiled GEMM: Hout[row][c] = sum_k X[row][k]*W[k][c] ------
// 4x4 outputs per thread; K chunked by KC; X staged transposed in LDS. Output f16.
template<typename XT, int K, int COLS, int BM, int KC>
__global__ __launch_bounds__((BM / 4) * (COLS / 4))
void gemm_tiled_h(const XT* __restrict__ X, const float* __restrict__ W,
                  __half* __restrict__ Hout, int rows) {
    constexpr int TM = 4, TN = 4;
    constexpr int NCG = COLS / TN;
    constexpr int NRG = BM / TM;
    constexpr int NT = NCG * NRG;
    constexpr int XPAD = BM + 4;
    __shared__ float Xs[KC][XPAD];
    __shared__ float Ws[KC][COLS];
    const int tid = threadIdx.x;
    const int cg = tid % NCG;
    const int rg = tid / NCG;
    const int row0 = blockIdx.x * BM;
    float acc[TM][TN] = {};
    for (int k0 = 0; k0 < K; k0 += KC) {
        const float4* wsrc = (const float4*)(W + (size_t)k0 * COLS);
        float4* wdst = (float4*)&Ws[0][0];
        #pragma unroll
        for (int idx = tid; idx < KC * COLS / 4; idx += NT) wdst[idx] = wsrc[idx];
        constexpr int F4R = KC / 4;
        #pragma unroll
        for (int idx = tid; idx < BM * F4R; idx += NT) {
            int row = idx / F4R, k4 = idx % F4R;
            float4 v = Vec4Loader<XT>::load(X + (size_t)(row0 + row) * K + k0 + 4 * k4);
            Xs[4 * k4 + 0][row] = v.x;
            Xs[4 * k4 + 1][row] = v.y;
            Xs[4 * k4 + 2][row] = v.z;
            Xs[4 * k4 + 3][row] = v.w;
        }
        __syncthreads();
        #pragma unroll
        for (int k = 0; k < KC; ++k) {
            float wr[TN], xr[TM];
            *(float4*)wr = *(const float4*)&Ws[k][TN * cg];
            *(float4*)xr = *(const float4*)&Xs[k][TM * rg];
            #pragma unroll
            for (int i = 0; i < TM; ++i)
                #pragma unroll
                for (int j = 0; j < TN; ++j)
                    acc[i][j] += xr[i] * wr[j];
        }
        __syncthreads();
    }
    #pragma unroll
    for (int i = 0; i < TM; ++i) {
        int row = row0 + TM * rg + i;
        if (row < rows) {
            __half2 h01 = __floats2half2_rn(acc[i][0], acc[i][1]);
            __half2 h23 = __floats2half2_rn(acc[i][2], acc[i][3]);
            uint2 pk;
            pk.x = *reinterpret_cast<unsigned int*>(&h01);
            pk.y = *reinterpret_cast<unsigned int*>(&h23);
            *reinterpret_cast<uint2*>(Hout + (size_t)row * COLS + TN * cg) = pk;
        }
    }
}

// ---------------- attention logits from f16 features ----------------
template<int H>
__global__ void att_logits_h(const __half* __restrict__ Hf,
                             const float* __restrict__ a_src,
                             const float* __restrict__ a_dst,
                             float* __restrict__ es, float* __restrict__ ed,
                             int rows) {
    int t = blockIdx.x * blockDim.x + threadIdx.x;
    if (t >= rows * H) return;
    int row = t / H, h = t % H;
    const __half2* hv = (const __half2*)(Hf + (size_t)row * (H * UNITS) + h * UNITS);
    const float* as = a_src + h * UNITS;
    const float* ad = a_dst + h * UNITS;
    float s = 0.f, d = 0.f;
    #pragma unroll
    for (int i = 0; i < UNITS / 2; ++i) {
        float2 xv = __half22float2(hv[i]);
        s += xv.x * as[2 * i] + xv.y * as[2 * i + 1];
        d += xv.x * ad[2 * i] + xv.y * ad[2 * i + 1];
    }
    es[t] = s;
    ed[t] = d;
}

// ---------------- CSR build ----------------
__global__ void deg_kernel(const int* __restrict__ edst, int* __restrict__ deg, int E) {
    int e = blockIdx.x * blockDim.x + threadIdx.x;
    if (e < E) atomicAdd(&deg[edst[e]], 1);
}

// 1024-thread shuffle-based scan: deg[N] -> exclusive row_ptr[N+1]
__global__ void scan_kernel(const int* __restrict__ deg, int* __restrict__ row_ptr, int N) {
    __shared__ int wsum[16];
    __shared__ int carryS;
    int tid = threadIdx.x;
    int wid = tid >> 6, lane = tid & 63;
    if (tid == 0) carryS = 0;
    __syncthreads();
    for (int base = 0; base < N; base += 1024) {
        int i = base + tid;
        int v = (i < N) ? deg[i] : 0;
        int x = v;
        #pragma unroll
        for (int off = 1; off < 64; off <<= 1) {
            int t = __shfl_up(x, off);
            if (lane >= off) x += t;
        }
        if (lane == 63) wsum[wid] = x;
        __syncthreads();
        if (wid == 0) {
            int s = (lane < 16) ? wsum[lane] : 0;
            #pragma unroll
            for (int off = 1; off < 16; off <<= 1) {
                int t = __shfl_up(s, off);
                if (lane >= off) s += t;
            }
            if (lane < 16) wsum[lane] = s;   // inclusive over wave sums
        }
        __syncthreads();
        int wbase = carryS + (wid ? wsum[wid - 1] : 0);
        if (i < N) row_ptr[i] = wbase + x - v;   // exclusive
        int total = wsum[15];
        __syncthreads();
        if (tid == 0) carryS += total;
        __syncthreads();
    }
    if (threadIdx.x == 0) row_ptr[N] = carryS;
}

__global__ void scatter_kernel(const int* __restrict__ esrc, const int* __restrict__ edst,
                               const int* __restrict__ row_ptr, int* __restrict__ cursor,
                               int* __restrict__ col, int E) {
    int e = blockIdx.x * blockDim.x + threadIdx.x;
    if (e >= E) return;
    int d = edst[e];
    int pos = atomicAdd(&cursor[d], 1);
    col[row_ptr[d] + pos] = esrc[e];
}

// ---------------- layer-1 aggregation: fused single pass ----------------
// out[d] = (sum_e expv_e * h_src) / (sum_e expv_e + 1e-9); division deferred to end.
// One wave per (b, d); lane owns cols {2*lane, 2*lane+1} (same head, h = lane>>4).
__global__ __launch_bounds__(512)
void agg1_kernel(const int* __restrict__ row_ptr, const int* __restrict__ col,
                 const float* __restrict__ es, const float* __restrict__ ed,
                 const __half* __restrict__ Hf, const float* __restrict__ bias,
                 __half* __restrict__ outH) {
    __shared__ float evS[8][64][4];   // 8 KB: unnormalized exp per wave per chunk-edge
    __shared__ int colS[64];
    int d = blockIdx.x;
    int b = threadIdx.x >> 6;
    int lane = threadIdx.x & 63;
    int start = row_ptr[d], end = row_ptr[d + 1];
    size_t brow = (size_t)b * N_NODES;
    size_t drow = brow + d;
    float4 ed4 = ((const float4*)ed)[drow];
    float dx = 0.f, dy = 0.f, dz = 0.f, dw = 0.f;   // per-lane denom partials
    float accx = 0.f, accy = 0.f;
    const __half2* hb = (const __half2*)Hf + ((size_t)brow << 6) + lane;  // +s*64
    for (int i0 = start; i0 < end; i0 += 64) {
        int nch = end - i0; if (nch > 64) nch = 64;
        __syncthreads();   // uniform trips: all waves share d
        if (lane < nch) {
            int s = col[i0 + lane];
            if (b == 0) colS[lane] = s;
            float4 e4 = ((const float4*)es)[brow + s];
            float l, a0, a1, a2, a3;
            l = e4.x + ed4.x; l = l > 0.f ? l : 0.2f * l; a0 = __expf(l); dx += a0;
            l = e4.y + ed4.y; l = l > 0.f ? l : 0.2f * l; a1 = __expf(l); dy += a1;
            l = e4.z + ed4.z; l = l > 0.f ? l : 0.2f * l; a2 = __expf(l); dz += a2;
            l = e4.w + ed4.w; l = l > 0.f ? l : 0.2f * l; a3 = __expf(l); dw += a3;
            *(float4*)&evS[b][lane][0] = make_float4(a0, a1, a2, a3);
        }
        __syncthreads();
        for (int t = 0; t < nch; ++t) {
            int s = colS[t];
            float4 a4 = *(const float4*)&evS[b][t][0];   // LDS broadcast
            float a = (lane & 32) ? ((lane & 16) ? a4.w : a4.z)
                                  : ((lane & 16) ? a4.y : a4.x);
            float2 hv = __half22float2(hb[(size_t)s << 6]);
            accx += a * hv.x;
            accy += a * hv.y;
        }
    }
    #pragma unroll
    for (int off = 32; off; off >>= 1) {
        dx += __shfl_xor(dx, off);
        dy += __shfl_xor(dy, off);
        dz += __shfl_xor(dz, off);
        dw += __shfl_xor(dw, off);
    }
    float ix = 1.f / (dx + 1e-9f);
    float iy = 1.f / (dy + 1e-9f);
    float iz = 1.f / (dz + 1e-9f);
    float iw = 1.f / (dw + 1e-9f);
    float inv = (lane & 32) ? ((lane & 16) ? iw : iz)
                            : ((lane & 16) ? iy : ix);
    float2 bv = *(const float2*)(bias + 2 * lane);
    float vx = fmaxf(accx * inv + bv.x, 0.f);
    float vy = fmaxf(accy * inv + bv.y, 0.f);
    __half2 h2o = __floats2half2_rn(vx, vy);
    ((__half2*)outH)[drow * 64 + lane] = h2o;
}

// ---------------- layer-2 aggregation: fused single pass ----------------
// lane = sub(2b) * 16 + c2; sub strides edges, c2 covers cols {2*c2, 2*c2+1}
__global__ __launch_bounds__(512)
void agg2_kernel(const int* __restrict__ row_ptr, const int* __restrict__ col,
                 const float* __restrict__ es, const float* __restrict__ ed,
                 const __half* __restrict__ Hf, const float* __restrict__ bias,
                 float* __restrict__ outF) {
    __shared__ float evS[8][64];   // 2 KB
    __shared__ int colS[64];
    int d = blockIdx.x;
    int b = threadIdx.x >> 6;
    int lane = threadIdx.x & 63;
    int sub = lane >> 4;
    int c2 = lane & 15;
    int start = row_ptr[d], end = row_ptr[d + 1];
    size_t brow = (size_t)b * N_NODES;
    size_t drow = brow + d;
    float edv = ed[drow];
    float den = 0.f;
    float accx = 0.f, accy = 0.f;
    const __half2* hb = (const __half2*)Hf + ((size_t)brow << 4) + c2;  // +s*16
    for (int i0 = start; i0 < end; i0 += 64) {
        int nch = end - i0; if (nch > 64) nch = 64;
        __syncthreads();
        if (lane < nch) {
            int s = col[i0 + lane];
            if (b == 0) colS[lane] = s;
            float l = es[brow + s] + edv;
            l = l > 0.f ? l : 0.2f * l;
            float ev = __expf(l);
            den += ev;
            evS[b][lane] = ev;
        }
        __syncthreads();
        for (int t = sub; t < nch; t += 4) {
            int s = colS[t];
            float a = evS[b][t];
            float2 hv = __half22float2(hb[(size_t)s << 4]);
            accx += a * hv.x;
            accy += a * hv.y;
        }
    }
    #pragma unroll
    for (int off = 32; off; off >>= 1) den += __shfl_xor(den, off);
    float inv = 1.f / (den + 1e-9f);
    accx += __shfl_xor(accx, 16); accx += __shfl_xor(accx, 32);
    accy += __shfl_xor(accy, 16); accy += __shfl_xor(accy, 32);
    if (sub == 0) {
        float2 bv = *(const float2*)(bias + 2 * c2);
        float2 o;
        o.x = accx * inv + bv.x;
        o.y = accy * inv + bv.y;
        *(float2*)(outF + drow * 32 + 2 * c2) = o;
    }
}

extern "C" void kernel_launch(void* const* d_in, const int* in_sizes, int n_in,
                              void* d_out, int out_size, void* d_ws, size_t ws_size,
                              hipStream_t stream) {
    const float* x    = (const float*)d_in[0];
    const int*   esrc = (const int*)d_in[1];
    const int*   edst = (const int*)d_in[2];
    const float* W1   = (const float*)d_in[3];
    const float* a1s  = (const float*)d_in[4];
    const float* a1d  = (const float*)d_in[5];
    const float* b1   = (const float*)d_in[6];
    const float* W2   = (const float*)d_in[7];
    const float* a2s  = (const float*)d_in[8];
    const float* a2d  = (const float*)d_in[9];
    const float* b2   = (const float*)d_in[10];
    float* out = (float*)d_out;
    const int E = in_sizes[1];
    const int rows = BATCH * N_NODES;  // 80000

    // workspace layout
    float* wsf = (float*)d_ws;
    __half* h1h   = (__half*)wsf;                       // rows*128 halfs
    float*  e1s   = wsf + (size_t)rows * 64;            // rows*4
    float*  e1d   = e1s + (size_t)rows * 4;             // rows*4
    __half* out1h = (__half*)(e1d + (size_t)rows * 4);  // rows*128 halfs
    int* deg      = (int*)((float*)out1h + (size_t)rows * 64);  // N
    int* cursor   = deg + N_NODES;                      // N
    int* row_ptr  = cursor + N_NODES;                   // N+1
    int* colIdx   = row_ptr + N_NODES + 1;              // E
    // layer 2 reuse
    __half* h2h = h1h;            // rows*32 halfs (h1h dead after agg1)
    float*  e2s = e1s;            // rows (e1s dead after agg1)
    float*  e2d = e1s + rows;     // rows

    const int TPB = 256;

    // ---------- CSR build (shared by both layers) ----------
    hipMemsetAsync(deg, 0, N_NODES * sizeof(int), stream);
    hipMemsetAsync(cursor, 0, N_NODES * sizeof(int), stream);
    deg_kernel<<<(E + TPB - 1) / TPB, TPB, 0, stream>>>(edst, deg, E);
    scan_kernel<<<1, 1024, 0, stream>>>(deg, row_ptr, N_NODES);
    scatter_kernel<<<(E + TPB - 1) / TPB, TPB, 0, stream>>>(esrc, edst, row_ptr, cursor, colIdx, E);

    // ---------- layer 1 ----------
    gemm_tiled_h<float, FIN, 128, 32, 32><<<rows / 32, 256, 0, stream>>>(x, W1, h1h, rows);
    att_logits_h<NH1><<<(rows * NH1 + TPB - 1) / TPB, TPB, 0, stream>>>(
        h1h, a1s, a1d, e1s, e1d, rows);
    agg1_kernel<<<N_NODES, 512, 0, stream>>>(row_ptr, colIdx, e1s, e1d, h1h, b1, out1h);

    // ---------- layer 2 ----------
    gemm_tiled_h<__half, 128, UNITS, 128, 32><<<rows / 128, 256, 0, stream>>>(out1h, W2, h2h, rows);
    att_logits_h<1><<<(rows + TPB - 1) / TPB, TPB, 0, stream>>>(
        h2h, a2s, a2d, e2s, e2d, rows);
    agg2_kernel<<<N_NODES, 512, 0, stream>>>(row_ptr, colIdx, e2s, e2d, h2h, b2, out);
}

// Round 6
// 289.298 us; speedup vs baseline: 8.3828x; 1.0485x over previous
//
#include <hip/hip_runtime.h>
#include <hip/hip_fp16.h>

#define N_NODES 10000
#define BATCH 8
#define FIN 128
#define UNITS 32
#define NH1 4

// ---------------- vec4 loader (f32 or f16 source) ----------------
template<typename T> struct Vec4Loader;
template<> struct Vec4Loader<float> {
    static __device__ inline float4 load(const float* p) { return *(const float4*)p; }
};
template<> struct Vec4Loader<__half> {
    static __device__ inline float4 load(const __half* p) {
        const __half2* p2 = (const __half2*)p;
        float2 a = __half22float2(p2[0]);
        float2 b = __half22float2(p2[1]);
        return make_float4(a.x, a.y, b.x, b.y);
    }
};

// ---------------- register-tiled GEMM: Hout[row][c] = sum_k X[row][k]*W[k][c] ------
template<typename XT, int K, int COLS, int BM, int KC>
__global__ __launch_bounds__((BM / 4) * (COLS / 4))
void gemm_tiled_h(const XT* __restrict__ X, const float* __restrict__ W,
                  __half* __restrict__ Hout, int rows) {
    constexpr int TM = 4, TN = 4;
    constexpr int NCG = COLS / TN;
    constexpr int NRG = BM / TM;
    constexpr int NT = NCG * NRG;
    constexpr int XPAD = BM + 4;
    __shared__ float Xs[KC][XPAD];
    __shared__ float Ws[KC][COLS];
    const int tid = threadIdx.x;
    const int cg = tid % NCG;
    const int rg = tid / NCG;
    const int row0 = blockIdx.x * BM;
    float acc[TM][TN] = {};
    for (int k0 = 0; k0 < K; k0 += KC) {
        const float4* wsrc = (const float4*)(W + (size_t)k0 * COLS);
        float4* wdst = (float4*)&Ws[0][0];
        #pragma unroll
        for (int idx = tid; idx < KC * COLS / 4; idx += NT) wdst[idx] = wsrc[idx];
        constexpr int F4R = KC / 4;
        #pragma unroll
        for (int idx = tid; idx < BM * F4R; idx += NT) {
            int row = idx / F4R, k4 = idx % F4R;
            float4 v = Vec4Loader<XT>::load(X + (size_t)(row0 + row) * K + k0 + 4 * k4);
            Xs[4 * k4 + 0][row] = v.x;
            Xs[4 * k4 + 1][row] = v.y;
            Xs[4 * k4 + 2][row] = v.z;
            Xs[4 * k4 + 3][row] = v.w;
        }
        __syncthreads();
        #pragma unroll
        for (int k = 0; k < KC; ++k) {
            float wr[TN], xr[TM];
            *(float4*)wr = *(const float4*)&Ws[k][TN * cg];
            *(float4*)xr = *(const float4*)&Xs[k][TM * rg];
            #pragma unroll
            for (int i = 0; i < TM; ++i)
                #pragma unroll
                for (int j = 0; j < TN; ++j)
                    acc[i][j] += xr[i] * wr[j];
        }
        __syncthreads();
    }
    #pragma unroll
    for (int i = 0; i < TM; ++i) {
        int row = row0 + TM * rg + i;
        if (row < rows) {
            __half2 h01 = __floats2half2_rn(acc[i][0], acc[i][1]);
            __half2 h23 = __floats2half2_rn(acc[i][2], acc[i][3]);
            uint2 pk;
            pk.x = *reinterpret_cast<unsigned int*>(&h01);
            pk.y = *reinterpret_cast<unsigned int*>(&h23);
            *reinterpret_cast<uint2*>(Hout + (size_t)row * COLS + TN * cg) = pk;
        }
    }
}

// ---------------- attention logits from f16 features ----------------
template<int H>
__global__ void att_logits_h(const __half* __restrict__ Hf,
                             const float* __restrict__ a_src,
                             const float* __restrict__ a_dst,
                             float* __restrict__ es, float* __restrict__ ed,
                             int rows) {
    int t = blockIdx.x * blockDim.x + threadIdx.x;
    if (t >= rows * H) return;
    int row = t / H, h = t % H;
    const __half2* hv = (const __half2*)(Hf + (size_t)row * (H * UNITS) + h * UNITS);
    const float* as = a_src + h * UNITS;
    const float* ad = a_dst + h * UNITS;
    float s = 0.f, d = 0.f;
    #pragma unroll
    for (int i = 0; i < UNITS / 2; ++i) {
        float2 xv = __half22float2(hv[i]);
        s += xv.x * as[2 * i] + xv.y * as[2 * i + 1];
        d += xv.x * ad[2 * i] + xv.y * ad[2 * i + 1];
    }
    es[t] = s;
    ed[t] = d;
}

// ---------------- CSR build ----------------
__global__ void deg_kernel(const int* __restrict__ edst, int* __restrict__ deg, int E) {
    int e = blockIdx.x * blockDim.x + threadIdx.x;
    if (e < E) atomicAdd(&deg[edst[e]], 1);
}

__global__ void scan_kernel(const int* __restrict__ deg, int* __restrict__ row_ptr, int N) {
    __shared__ int wsum[16];
    __shared__ int carryS;
    int tid = threadIdx.x;
    int wid = tid >> 6, lane = tid & 63;
    if (tid == 0) carryS = 0;
    __syncthreads();
    for (int base = 0; base < N; base += 1024) {
        int i = base + tid;
        int v = (i < N) ? deg[i] : 0;
        int x = v;
        #pragma unroll
        for (int off = 1; off < 64; off <<= 1) {
            int t = __shfl_up(x, off);
            if (lane >= off) x += t;
        }
        if (lane == 63) wsum[wid] = x;
        __syncthreads();
        if (wid == 0) {
            int s = (lane < 16) ? wsum[lane] : 0;
            #pragma unroll
            for (int off = 1; off < 16; off <<= 1) {
                int t = __shfl_up(s, off);
                if (lane >= off) s += t;
            }
            if (lane < 16) wsum[lane] = s;
        }
        __syncthreads();
        int wbase = carryS + (wid ? wsum[wid - 1] : 0);
        if (i < N) row_ptr[i] = wbase + x - v;
        int total = wsum[15];
        __syncthreads();
        if (tid == 0) carryS += total;
        __syncthreads();
    }
    if (threadIdx.x == 0) row_ptr[N] = carryS;
}

__global__ void scatter_kernel(const int* __restrict__ esrc, const int* __restrict__ edst,
                               const int* __restrict__ row_ptr, int* __restrict__ cursor,
                               int* __restrict__ col, int E) {
    int e = blockIdx.x * blockDim.x + threadIdx.x;
    if (e >= E) return;
    int d = edst[e];
    int pos = atomicAdd(&cursor[d], 1);
    col[row_ptr[d] + pos] = esrc[e];
}

// ---------------- layer-1 aggregation: fused single pass, 4 edges/wave-iter --------
// One wave per (b, d). Accumulate loop: eg = lane>>4 picks edge, c8 = lane&15 owns
// cols 8*c8..8*c8+7 (one dwordx4 f16 load). Deferred normalization.
__global__ __launch_bounds__(512)
void agg1_kernel(const int* __restrict__ row_ptr, const int* __restrict__ col,
                 const float* __restrict__ es, const float* __restrict__ ed,
                 const __half* __restrict__ Hf, const float* __restrict__ bias,
                 __half* __restrict__ outH) {
    __shared__ float evS[8][64][4];   // 8 KB
    __shared__ int colS[64];
    int d = blockIdx.x;
    int b = threadIdx.x >> 6;
    int lane = threadIdx.x & 63;
    int eg = lane >> 4;
    int c8 = lane & 15;
    int head = c8 >> 2;
    int start = row_ptr[d], end = row_ptr[d + 1];
    size_t brow = (size_t)b * N_NODES;
    size_t drow = brow + d;
    float4 ed4 = ((const float4*)ed)[drow];
    float dx = 0.f, dy = 0.f, dz = 0.f, dw = 0.f;
    float acc[8] = {};
    const __half* hbase = Hf + (brow << 7);   // + s*128 + c8*8
    for (int i0 = start; i0 < end; i0 += 64) {
        int nch = end - i0; if (nch > 64) nch = 64;
        __syncthreads();   // uniform trips: all waves share d
        if (lane < nch) {
            int s = col[i0 + lane];
            if (b == 0) colS[lane] = s;
            float4 e4 = ((const float4*)es)[brow + s];
            float l, a0, a1, a2, a3;
            l = e4.x + ed4.x; l = l > 0.f ? l : 0.2f * l; a0 = __expf(l); dx += a0;
            l = e4.y + ed4.y; l = l > 0.f ? l : 0.2f * l; a1 = __expf(l); dy += a1;
            l = e4.z + ed4.z; l = l > 0.f ? l : 0.2f * l; a2 = __expf(l); dz += a2;
            l = e4.w + ed4.w; l = l > 0.f ? l : 0.2f * l; a3 = __expf(l); dw += a3;
            *(float4*)&evS[b][lane][0] = make_float4(a0, a1, a2, a3);
        }
        __syncthreads();
        for (int t = 0; t < nch; t += 4) {
            int myt = t + eg;
            int tt = myt < nch ? myt : 0;
            float a = evS[b][tt][head];
            if (myt >= nch) a = 0.f;
            int s = colS[tt];
            float4 raw = *(const float4*)(hbase + ((size_t)s << 7) + (c8 << 3));
            const __half2* hh = (const __half2*)&raw;
            #pragma unroll
            for (int j = 0; j < 4; ++j) {
                float2 f = __half22float2(hh[j]);
                acc[2 * j]     += a * f.x;
                acc[2 * j + 1] += a * f.y;
            }
        }
    }
    #pragma unroll
    for (int off = 32; off; off >>= 1) {
        dx += __shfl_xor(dx, off);
        dy += __shfl_xor(dy, off);
        dz += __shfl_xor(dz, off);
        dw += __shfl_xor(dw, off);
    }
    float ix = 1.f / (dx + 1e-9f);
    float iy = 1.f / (dy + 1e-9f);
    float iz = 1.f / (dz + 1e-9f);
    float iw = 1.f / (dw + 1e-9f);
    float inv = (head & 2) ? ((head & 1) ? iw : iz) : ((head & 1) ? iy : ix);
    #pragma unroll
    for (int j = 0; j < 8; ++j) {
        acc[j] += __shfl_xor(acc[j], 16);
        acc[j] += __shfl_xor(acc[j], 32);
    }
    if (eg == 0) {
        float4 b0 = *(const float4*)(bias + 8 * c8);
        float4 b1 = *(const float4*)(bias + 8 * c8 + 4);
        const float* bv = &b0.x;   // b0,b1 contiguous on stack? use explicit
        float vals[8];
        vals[0] = fmaxf(acc[0] * inv + b0.x, 0.f);
        vals[1] = fmaxf(acc[1] * inv + b0.y, 0.f);
        vals[2] = fmaxf(acc[2] * inv + b0.z, 0.f);
        vals[3] = fmaxf(acc[3] * inv + b0.w, 0.f);
        vals[4] = fmaxf(acc[4] * inv + b1.x, 0.f);
        vals[5] = fmaxf(acc[5] * inv + b1.y, 0.f);
        vals[6] = fmaxf(acc[6] * inv + b1.z, 0.f);
        vals[7] = fmaxf(acc[7] * inv + b1.w, 0.f);
        (void)bv;
        __half2 o[4];
        #pragma unroll
        for (int j = 0; j < 4; ++j) o[j] = __floats2half2_rn(vals[2 * j], vals[2 * j + 1]);
        *(float4*)(outH + drow * 128 + c8 * 8) = *(float4*)o;
    }
}

// ---------------- layer-2 aggregation: fused single pass, 16 edges/wave-iter -------
// eg = lane>>2 picks edge, c8 = lane&3 owns cols 8*c8..8*c8+7.
__global__ __launch_bounds__(512)
void agg2_kernel(const int* __restrict__ row_ptr, const int* __restrict__ col,
                 const float* __restrict__ es, const float* __restrict__ ed,
                 const __half* __restrict__ Hf, const float* __restrict__ bias,
                 float* __restrict__ outF) {
    __shared__ float evS[8][64];   // 2 KB
    __shared__ int colS[64];
    int d = blockIdx.x;
    int b = threadIdx.x >> 6;
    int lane = threadIdx.x & 63;
    int eg = lane >> 2;
    int c8 = lane & 3;
    int start = row_ptr[d], end = row_ptr[d + 1];
    size_t brow = (size_t)b * N_NODES;
    size_t drow = brow + d;
    float edv = ed[drow];
    float den = 0.f;
    float acc[8] = {};
    const __half* hbase = Hf + (brow << 5);   // + s*32 + c8*8
    for (int i0 = start; i0 < end; i0 += 64) {
        int nch = end - i0; if (nch > 64) nch = 64;
        __syncthreads();
        if (lane < nch) {
            int s = col[i0 + lane];
            if (b == 0) colS[lane] = s;
            float l = es[brow + s] + edv;
            l = l > 0.f ? l : 0.2f * l;
            float ev = __expf(l);
            den += ev;
            evS[b][lane] = ev;
        }
        __syncthreads();
        for (int t = 0; t < nch; t += 16) {
            int myt = t + eg;
            int tt = myt < nch ? myt : 0;
            float a = evS[b][tt];
            if (myt >= nch) a = 0.f;
            int s = colS[tt];
            float4 raw = *(const float4*)(hbase + ((size_t)s << 5) + (c8 << 3));
            const __half2* hh = (const __half2*)&raw;
            #pragma unroll
            for (int j = 0; j < 4; ++j) {
                float2 f = __half22float2(hh[j]);
                acc[2 * j]     += a * f.x;
                acc[2 * j + 1] += a * f.y;
            }
        }
    }
    #pragma unroll
    for (int off = 32; off; off >>= 1) den += __shfl_xor(den, off);
    float inv = 1.f / (den + 1e-9f);
    #pragma unroll
    for (int j = 0; j < 8; ++j) {
        acc[j] += __shfl_xor(acc[j], 4);
        acc[j] += __shfl_xor(acc[j], 8);
        acc[j] += __shfl_xor(acc[j], 16);
        acc[j] += __shfl_xor(acc[j], 32);
    }
    if (eg == 0) {
        float4 b0 = *(const float4*)(bias + 8 * c8);
        float4 b1 = *(const float4*)(bias + 8 * c8 + 4);
        float4 o0, o1;
        o0.x = acc[0] * inv + b0.x;
        o0.y = acc[1] * inv + b0.y;
        o0.z = acc[2] * inv + b0.z;
        o0.w = acc[3] * inv + b0.w;
        o1.x = acc[4] * inv + b1.x;
        o1.y = acc[5] * inv + b1.y;
        o1.z = acc[6] * inv + b1.z;
        o1.w = acc[7] * inv + b1.w;
        float* op = outF + drow * 32 + 8 * c8;
        *(float4*)op = o0;
        *(float4*)(op + 4) = o1;
    }
}

extern "C" void kernel_launch(void* const* d_in, const int* in_sizes, int n_in,
                              void* d_out, int out_size, void* d_ws, size_t ws_size,
                              hipStream_t stream) {
    const float* x    = (const float*)d_in[0];
    const int*   esrc = (const int*)d_in[1];
    const int*   edst = (const int*)d_in[2];
    const float* W1   = (const float*)d_in[3];
    const float* a1s  = (const float*)d_in[4];
    const float* a1d  = (const float*)d_in[5];
    const float* b1   = (const float*)d_in[6];
    const float* W2   = (const float*)d_in[7];
    const float* a2s  = (const float*)d_in[8];
    const float* a2d  = (const float*)d_in[9];
    const float* b2   = (const float*)d_in[10];
    float* out = (float*)d_out;
    const int E = in_sizes[1];
    const int rows = BATCH * N_NODES;  // 80000

    // workspace layout
    float* wsf = (float*)d_ws;
    __half* h1h   = (__half*)wsf;                       // rows*128 halfs
    float*  e1s   = wsf + (size_t)rows * 64;            // rows*4
    float*  e1d   = e1s + (size_t)rows * 4;             // rows*4
    __half* out1h = (__half*)(e1d + (size_t)rows * 4);  // rows*128 halfs
    int* deg      = (int*)((float*)out1h + (size_t)rows * 64);  // N
    int* cursor   = deg + N_NODES;                      // N
    int* row_ptr  = cursor + N_NODES;                   // N+1
    int* colIdx   = row_ptr + N_NODES + 1;              // E
    // layer 2 reuse
    __half* h2h = h1h;
    float*  e2s = e1s;
    float*  e2d = e1s + rows;

    const int TPB = 256;

    // ---------- CSR build (shared by both layers) ----------
    hipMemsetAsync(deg, 0, N_NODES * sizeof(int), stream);
    hipMemsetAsync(cursor, 0, N_NODES * sizeof(int), stream);
    deg_kernel<<<(E + TPB - 1) / TPB, TPB, 0, stream>>>(edst, deg, E);
    scan_kernel<<<1, 1024, 0, stream>>>(deg, row_ptr, N_NODES);
    scatter_kernel<<<(E + TPB - 1) / TPB, TPB, 0, stream>>>(esrc, edst, row_ptr, cursor, colIdx, E);

    // ---------- layer 1 ----------
    gemm_tiled_h<float, FIN, 128, 32, 32><<<rows / 32, 256, 0, stream>>>(x, W1, h1h, rows);
    att_logits_h<NH1><<<(rows * NH1 + TPB - 1) / TPB, TPB, 0, stream>>>(
        h1h, a1s, a1d, e1s, e1d, rows);
    agg1_kernel<<<N_NODES, 512, 0, stream>>>(row_ptr, colIdx, e1s, e1d, h1h, b1, out1h);

    // ---------- layer 2 ----------
    gemm_tiled_h<__half, 128, UNITS, 128, 32><<<rows / 128, 256, 0, stream>>>(out1h, W2, h2h, rows);
    att_logits_h<1><<<(rows + TPB - 1) / TPB, TPB, 0, stream>>>(
        h2h, a2s, a2d, e2s, e2d, rows);
    agg2_kernel<<<N_NODES, 512, 0, stream>>>(row_ptr, colIdx, e2s, e2d, h2h, b2, out);
}

// Round 7
// 236.450 us; speedup vs baseline: 10.2563x; 1.2235x over previous
//
#include <hip/hip_runtime.h>
#include <hip/hip_fp16.h>

#define N_NODES 10000
#define BATCH 8
#define FIN 128
#define UNITS 32
#define NH1 4

#define WAVE_FENCE() asm volatile("s_waitcnt lgkmcnt(0)" ::: "memory")

// ---------------- vec4 loader (f32 or f16 source) ----------------
template<typename T> struct Vec4Loader;
template<> struct Vec4Loader<float> {
    static __device__ inline float4 load(const float* p) { return *(const float4*)p; }
};
template<> struct Vec4Loader<__half> {
    static __device__ inline float4 load(const __half* p) {
        const __half2* p2 = (const __half2*)p;
        float2 a = __half22float2(p2[0]);
        float2 b = __half22float2(p2[1]);
        return make_float4(a.x, a.y, b.x, b.y);
    }
};

// ---------------- register-tiled GEMM: Hout[row][c] = sum_k X[row][k]*W[k][c] ------
template<typename XT, int K, int COLS, int BM, int KC>
__global__ __launch_bounds__((BM / 4) * (COLS / 4))
void gemm_tiled_h(const XT* __restrict__ X, const float* __restrict__ W,
                  __half* __restrict__ Hout, int rows) {
    constexpr int TM = 4, TN = 4;
    constexpr int NCG = COLS / TN;
    constexpr int NRG = BM / TM;
    constexpr int NT = NCG * NRG;
    constexpr int XPAD = BM + 4;
    __shared__ float Xs[KC][XPAD];
    __shared__ float Ws[KC][COLS];
    const int tid = threadIdx.x;
    const int cg = tid % NCG;
    const int rg = tid / NCG;
    const int row0 = blockIdx.x * BM;
    float acc[TM][TN] = {};
    for (int k0 = 0; k0 < K; k0 += KC) {
        const float4* wsrc = (const float4*)(W + (size_t)k0 * COLS);
        float4* wdst = (float4*)&Ws[0][0];
        #pragma unroll
        for (int idx = tid; idx < KC * COLS / 4; idx += NT) wdst[idx] = wsrc[idx];
        constexpr int F4R = KC / 4;
        #pragma unroll
        for (int idx = tid; idx < BM * F4R; idx += NT) {
            int row = idx / F4R, k4 = idx % F4R;
            float4 v = Vec4Loader<XT>::load(X + (size_t)(row0 + row) * K + k0 + 4 * k4);
            Xs[4 * k4 + 0][row] = v.x;
            Xs[4 * k4 + 1][row] = v.y;
            Xs[4 * k4 + 2][row] = v.z;
            Xs[4 * k4 + 3][row] = v.w;
        }
        __syncthreads();
        #pragma unroll
        for (int k = 0; k < KC; ++k) {
            float wr[TN], xr[TM];
            *(float4*)wr = *(const float4*)&Ws[k][TN * cg];
            *(float4*)xr = *(const float4*)&Xs[k][TM * rg];
            #pragma unroll
            for (int i = 0; i < TM; ++i)
                #pragma unroll
                for (int j = 0; j < TN; ++j)
                    acc[i][j] += xr[i] * wr[j];
        }
        __syncthreads();
    }
    #pragma unroll
    for (int i = 0; i < TM; ++i) {
        int row = row0 + TM * rg + i;
        if (row < rows) {
            __half2 h01 = __floats2half2_rn(acc[i][0], acc[i][1]);
            __half2 h23 = __floats2half2_rn(acc[i][2], acc[i][3]);
            uint2 pk;
            pk.x = *reinterpret_cast<unsigned int*>(&h01);
            pk.y = *reinterpret_cast<unsigned int*>(&h23);
            *reinterpret_cast<uint2*>(Hout + (size_t)row * COLS + TN * cg) = pk;
        }
    }
}

// ---------------- attention logits from f16 features ----------------
template<int H>
__global__ void att_logits_h(const __half* __restrict__ Hf,
                             const float* __restrict__ a_src,
                             const float* __restrict__ a_dst,
                             float* __restrict__ es, float* __restrict__ ed,
                             int rows) {
    int t = blockIdx.x * blockDim.x + threadIdx.x;
    if (t >= rows * H) return;
    int row = t / H, h = t % H;
    const __half2* hv = (const __half2*)(Hf + (size_t)row * (H * UNITS) + h * UNITS);
    const float* as = a_src + h * UNITS;
    const float* ad = a_dst + h * UNITS;
    float s = 0.f, d = 0.f;
    #pragma unroll
    for (int i = 0; i < UNITS / 2; ++i) {
        float2 xv = __half22float2(hv[i]);
        s += xv.x * as[2 * i] + xv.y * as[2 * i + 1];
        d += xv.x * ad[2 * i] + xv.y * ad[2 * i + 1];
    }
    es[t] = s;
    ed[t] = d;
}

// ---------------- CSR build ----------------
__global__ void deg_kernel(const int* __restrict__ edst, int* __restrict__ deg, int E) {
    int e = blockIdx.x * blockDim.x + threadIdx.x;
    if (e < E) atomicAdd(&deg[edst[e]], 1);
}

__global__ void scan_kernel(const int* __restrict__ deg, int* __restrict__ row_ptr, int N) {
    __shared__ int wsum[16];
    __shared__ int carryS;
    int tid = threadIdx.x;
    int wid = tid >> 6, lane = tid & 63;
    if (tid == 0) carryS = 0;
    __syncthreads();
    for (int base = 0; base < N; base += 1024) {
        int i = base + tid;
        int v = (i < N) ? deg[i] : 0;
        int x = v;
        #pragma unroll
        for (int off = 1; off < 64; off <<= 1) {
            int t = __shfl_up(x, off);
            if (lane >= off) x += t;
        }
        if (lane == 63) wsum[wid] = x;
        __syncthreads();
        if (wid == 0) {
            int s = (lane < 16) ? wsum[lane] : 0;
            #pragma unroll
            for (int off = 1; off < 16; off <<= 1) {
                int t = __shfl_up(s, off);
                if (lane >= off) s += t;
            }
            if (lane < 16) wsum[lane] = s;
        }
        __syncthreads();
        int wbase = carryS + (wid ? wsum[wid - 1] : 0);
        if (i < N) row_ptr[i] = wbase + x - v;
        int total = wsum[15];
        __syncthreads();
        if (tid == 0) carryS += total;
        __syncthreads();
    }
    if (threadIdx.x == 0) row_ptr[N] = carryS;
}

__global__ void scatter_kernel(const int* __restrict__ esrc, const int* __restrict__ edst,
                               const int* __restrict__ row_ptr, int* __restrict__ cursor,
                               int* __restrict__ col, int E) {
    int e = blockIdx.x * blockDim.x + threadIdx.x;
    if (e >= E) return;
    int d = edst[e];
    int pos = atomicAdd(&cursor[d], 1);
    col[row_ptr[d] + pos] = esrc[e];
}

// ---------------- layer-1 aggregation ----------------
// Batch-per-XCD swizzle: b = blockIdx.x & 7 (blocks round-robin over 8 XCDs), so each
// XCD's L2 holds only batch b's h1 slice (2.56 MB < 4 MB). 8 waves/block = 8 nodes of
// the same batch; waves are independent (per-wave LDS slice + lgkmcnt fences, no
// __syncthreads -> divergent degree loops are safe).
__global__ __launch_bounds__(512)
void agg1_kernel(const int* __restrict__ row_ptr, const int* __restrict__ col,
                 const float* __restrict__ es, const float* __restrict__ ed,
                 const __half* __restrict__ Hf, const float* __restrict__ bias,
                 __half* __restrict__ outH) {
    __shared__ float evS[8][64][4];   // 8 KB, per-wave slice
    __shared__ int colS[8][64];       // 2 KB, per-wave slice
    int blk = blockIdx.x;
    int b = blk & 7;                  // batch -> XCD
    int grp = blk >> 3;
    int w = threadIdx.x >> 6;
    int d = grp * 8 + w;
    int lane = threadIdx.x & 63;
    int eg = lane >> 4;
    int c8 = lane & 15;
    int head = c8 >> 2;
    int start = row_ptr[d], end = row_ptr[d + 1];
    size_t brow = (size_t)b * N_NODES;
    size_t drow = brow + d;
    float4 ed4 = ((const float4*)ed)[drow];
    float dx = 0.f, dy = 0.f, dz = 0.f, dw = 0.f;
    float acc[8] = {};
    const __half* hbase = Hf + (brow << 7);
    for (int i0 = start; i0 < end; i0 += 64) {
        int nch = end - i0; if (nch > 64) nch = 64;
        WAVE_FENCE();   // WAR: prior chunk's LDS reads complete before overwrite
        if (lane < nch) {
            int s = col[i0 + lane];
            colS[w][lane] = s;
            float4 e4 = ((const float4*)es)[brow + s];
            float l, a0, a1, a2, a3;
            l = e4.x + ed4.x; l = l > 0.f ? l : 0.2f * l; a0 = __expf(l); dx += a0;
            l = e4.y + ed4.y; l = l > 0.f ? l : 0.2f * l; a1 = __expf(l); dy += a1;
            l = e4.z + ed4.z; l = l > 0.f ? l : 0.2f * l; a2 = __expf(l); dz += a2;
            l = e4.w + ed4.w; l = l > 0.f ? l : 0.2f * l; a3 = __expf(l); dw += a3;
            *(float4*)&evS[w][lane][0] = make_float4(a0, a1, a2, a3);
        }
        WAVE_FENCE();   // RAW: writes visible to all lanes of this wave
        for (int t = 0; t < nch; t += 4) {
            int myt = t + eg;
            int tt = myt < nch ? myt : 0;
            float a = evS[w][tt][head];
            if (myt >= nch) a = 0.f;
            int s = colS[w][tt];
            float4 raw = *(const float4*)(hbase + ((size_t)s << 7) + (c8 << 3));
            const __half2* hh = (const __half2*)&raw;
            #pragma unroll
            for (int j = 0; j < 4; ++j) {
                float2 f = __half22float2(hh[j]);
                acc[2 * j]     += a * f.x;
                acc[2 * j + 1] += a * f.y;
            }
        }
    }
    #pragma unroll
    for (int off = 32; off; off >>= 1) {
        dx += __shfl_xor(dx, off);
        dy += __shfl_xor(dy, off);
        dz += __shfl_xor(dz, off);
        dw += __shfl_xor(dw, off);
    }
    float ix = 1.f / (dx + 1e-9f);
    float iy = 1.f / (dy + 1e-9f);
    float iz = 1.f / (dz + 1e-9f);
    float iw = 1.f / (dw + 1e-9f);
    float inv = (head & 2) ? ((head & 1) ? iw : iz) : ((head & 1) ? iy : ix);
    #pragma unroll
    for (int j = 0; j < 8; ++j) {
        acc[j] += __shfl_xor(acc[j], 16);
        acc[j] += __shfl_xor(acc[j], 32);
    }
    if (eg == 0) {
        float4 b0 = *(const float4*)(bias + 8 * c8);
        float4 b1 = *(const float4*)(bias + 8 * c8 + 4);
        float vals[8];
        vals[0] = fmaxf(acc[0] * inv + b0.x, 0.f);
        vals[1] = fmaxf(acc[1] * inv + b0.y, 0.f);
        vals[2] = fmaxf(acc[2] * inv + b0.z, 0.f);
        vals[3] = fmaxf(acc[3] * inv + b0.w, 0.f);
        vals[4] = fmaxf(acc[4] * inv + b1.x, 0.f);
        vals[5] = fmaxf(acc[5] * inv + b1.y, 0.f);
        vals[6] = fmaxf(acc[6] * inv + b1.z, 0.f);
        vals[7] = fmaxf(acc[7] * inv + b1.w, 0.f);
        __half2 o[4];
        #pragma unroll
        for (int j = 0; j < 4; ++j) o[j] = __floats2half2_rn(vals[2 * j], vals[2 * j + 1]);
        *(float4*)(outH + drow * 128 + c8 * 8) = *(float4*)o;
    }
}

// ---------------- layer-2 aggregation (same swizzle; 16 edges/wave-iter) ----------
__global__ __launch_bounds__(512)
void agg2_kernel(const int* __restrict__ row_ptr, const int* __restrict__ col,
                 const float* __restrict__ es, const float* __restrict__ ed,
                 const __half* __restrict__ Hf, const float* __restrict__ bias,
                 float* __restrict__ outF) {
    __shared__ float evS[8][64];
    __shared__ int colS[8][64];
    int blk = blockIdx.x;
    int b = blk & 7;
    int grp = blk >> 3;
    int w = threadIdx.x >> 6;
    int d = grp * 8 + w;
    int lane = threadIdx.x & 63;
    int eg = lane >> 2;
    int c8 = lane & 3;
    int start = row_ptr[d], end = row_ptr[d + 1];
    size_t brow = (size_t)b * N_NODES;
    size_t drow = brow + d;
    float edv = ed[drow];
    float den = 0.f;
    float acc[8] = {};
    const __half* hbase = Hf + (brow << 5);
    for (int i0 = start; i0 < end; i0 += 64) {
        int nch = end - i0; if (nch > 64) nch = 64;
        WAVE_FENCE();
        if (lane < nch) {
            int s = col[i0 + lane];
            colS[w][lane] = s;
            float l = es[brow + s] + edv;
            l = l > 0.f ? l : 0.2f * l;
            float ev = __expf(l);
            den += ev;
            evS[w][lane] = ev;
        }
        WAVE_FENCE();
        for (int t = 0; t < nch; t += 16) {
            int myt = t + eg;
            int tt = myt < nch ? myt : 0;
            float a = evS[w][tt];
            if (myt >= nch) a = 0.f;
            int s = colS[w][tt];
            float4 raw = *(const float4*)(hbase + ((size_t)s << 5) + (c8 << 3));
            const __half2* hh = (const __half2*)&raw;
            #pragma unroll
            for (int j = 0; j < 4; ++j) {
                float2 f = __half22float2(hh[j]);
                acc[2 * j]     += a * f.x;
                acc[2 * j + 1] += a * f.y;
            }
        }
    }
    #pragma unroll
    for (int off = 32; off; off >>= 1) den += __shfl_xor(den, off);
    float inv = 1.f / (den + 1e-9f);
    #pragma unroll
    for (int j = 0; j < 8; ++j) {
        acc[j] += __shfl_xor(acc[j], 4);
        acc[j] += __shfl_xor(acc[j], 8);
        acc[j] += __shfl_xor(acc[j], 16);
        acc[j] += __shfl_xor(acc[j], 32);
    }
    if (eg == 0) {
        float4 b0 = *(const float4*)(bias + 8 * c8);
        float4 b1 = *(const float4*)(bias + 8 * c8 + 4);
        float4 o0, o1;
        o0.x = acc[0] * inv + b0.x;
        o0.y = acc[1] * inv + b0.y;
        o0.z = acc[2] * inv + b0.z;
        o0.w = acc[3] * inv + b0.w;
        o1.x = acc[4] * inv + b1.x;
        o1.y = acc[5] * inv + b1.y;
        o1.z = acc[6] * inv + b1.z;
        o1.w = acc[7] * inv + b1.w;
        float* op = outF + drow * 32 + 8 * c8;
        *(float4*)op = o0;
        *(float4*)(op + 4) = o1;
    }
}

extern "C" void kernel_launch(void* const* d_in, const int* in_sizes, int n_in,
                              void* d_out, int out_size, void* d_ws, size_t ws_size,
                              hipStream_t stream) {
    const float* x    = (const float*)d_in[0];
    const int*   esrc = (const int*)d_in[1];
    const int*   edst = (const int*)d_in[2];
    const float* W1   = (const float*)d_in[3];
    const float* a1s  = (const float*)d_in[4];
    const float* a1d  = (const float*)d_in[5];
    const float* b1   = (const float*)d_in[6];
    const float* W2   = (const float*)d_in[7];
    const float* a2s  = (const float*)d_in[8];
    const float* a2d  = (const float*)d_in[9];
    const float* b2   = (const float*)d_in[10];
    float* out = (float*)d_out;
    const int E = in_sizes[1];
    const int rows = BATCH * N_NODES;  // 80000

    // workspace layout
    float* wsf = (float*)d_ws;
    __half* h1h   = (__half*)wsf;                       // rows*128 halfs
    float*  e1s   = wsf + (size_t)rows * 64;            // rows*4
    float*  e1d   = e1s + (size_t)rows * 4;             // rows*4
    __half* out1h = (__half*)(e1d + (size_t)rows * 4);  // rows*128 halfs
    int* deg      = (int*)((float*)out1h + (size_t)rows * 64);  // N
    int* cursor   = deg + N_NODES;                      // N
    int* row_ptr  = cursor + N_NODES;                   // N+1
    int* colIdx   = row_ptr + N_NODES + 1;              // E
    // layer 2 reuse
    __half* h2h = h1h;
    float*  e2s = e1s;
    float*  e2d = e1s + rows;

    const int TPB = 256;

    // ---------- CSR build (shared by both layers) ----------
    hipMemsetAsync(deg, 0, N_NODES * sizeof(int), stream);
    hipMemsetAsync(cursor, 0, N_NODES * sizeof(int), stream);
    deg_kernel<<<(E + TPB - 1) / TPB, TPB, 0, stream>>>(edst, deg, E);
    scan_kernel<<<1, 1024, 0, stream>>>(deg, row_ptr, N_NODES);
    scatter_kernel<<<(E + TPB - 1) / TPB, TPB, 0, stream>>>(esrc, edst, row_ptr, cursor, colIdx, E);

    // ---------- layer 1 ----------
    gemm_tiled_h<float, FIN, 128, 32, 32><<<rows / 32, 256, 0, stream>>>(x, W1, h1h, rows);
    att_logits_h<NH1><<<(rows * NH1 + TPB - 1) / TPB, TPB, 0, stream>>>(
        h1h, a1s, a1d, e1s, e1d, rows);
    agg1_kernel<<<(N_NODES / 8) * BATCH, 512, 0, stream>>>(row_ptr, colIdx, e1s, e1d, h1h, b1, out1h);

    // ---------- layer 2 ----------
    gemm_tiled_h<__half, 128, UNITS, 128, 32><<<rows / 128, 256, 0, stream>>>(out1h, W2, h2h, rows);
    att_logits_h<1><<<(rows + TPB - 1) / TPB, TPB, 0, stream>>>(
        h2h, a2s, a2d, e2s, e2d, rows);
    agg2_kernel<<<(N_NODES / 8) * BATCH, 512, 0, stream>>>(row_ptr, colIdx, e2s, e2d, h2h, b2, out);
}